// Round 1
// baseline (1604.929 us; speedup 1.0000x reference)
//
#include <hip/hip_runtime.h>
#include <math.h>

#define SEQ    2048
#define DMODEL 768
#define NHEAD  12
#define NEXP   8
#define IDIM   1024
#define ISH    2048

// ---------------------------------------------------------------- zero init
__global__ void zero_kernel(float* __restrict__ ybuf, int* __restrict__ counts) {
  int idx = blockIdx.x * blockDim.x + threadIdx.x;
  if (idx < SEQ * DMODEL / 4) {
    float4 z; z.x = z.y = z.z = z.w = 0.f;
    ((float4*)ybuf)[idx] = z;
  }
  if (idx < NEXP) counts[idx] = 0;
}

// ---------------------------------------------------------------- rmsnorm
__global__ __launch_bounds__(256) void rmsnorm_kernel(const float* __restrict__ in,
                                                      const float* __restrict__ w,
                                                      float* __restrict__ out) {
  int row = blockIdx.x;
  int tid = threadIdx.x;
  const float* r = in + (size_t)row * DMODEL;
  float v0 = r[tid], v1 = r[tid + 256], v2 = r[tid + 512];
  float ss = v0 * v0 + v1 * v1 + v2 * v2;
  __shared__ float red[256];
  red[tid] = ss;
  __syncthreads();
  for (int s = 128; s > 0; s >>= 1) {
    if (tid < s) red[tid] += red[tid + s];
    __syncthreads();
  }
  float rms = rsqrtf(red[0] * (1.f / DMODEL) + 1e-5f);
  float* o = out + (size_t)row * DMODEL;
  o[tid]       = v0 * rms * w[tid];
  o[tid + 256] = v1 * rms * w[tid + 256];
  o[tid + 512] = v2 * rms * w[tid + 512];
}

// ---------------------------------------------------------------- attention
// Flash-style: per (head, 64-q-row tile); K-tile == V-tile (Q=K=V=xn).
// outbuf = x + attn_out (residual fused).
__global__ __launch_bounds__(256) void attn_kernel(const float* __restrict__ xn,
                                                   const float* __restrict__ x,
                                                   float* __restrict__ outbuf) {
  __shared__ float Qt[64][68];   // pad 68: staging float4-aligned (272B), reads 2-way max
  __shared__ float Kt[64][68];
  __shared__ float St[64][68];
  __shared__ float mrow[64], lrow[64], arow[64];
  const int h = blockIdx.y;
  const int q0 = blockIdx.x * 64;
  const int tid = threadIdx.x;
  const int tx = tid & 15, ty = tid >> 4;

#pragma unroll
  for (int i = 0; i < 4; i++) {
    int fid = tid + i * 256;
    int r = fid >> 4, c4 = (fid & 15) << 2;
    *(float4*)&Qt[r][c4] = *(const float4*)(xn + (size_t)(q0 + r) * DMODEL + h * 64 + c4);
  }
  if (tid < 64) { mrow[tid] = -INFINITY; lrow[tid] = 0.f; }
  float o[4][4] = {};
  __syncthreads();

  for (int kt = 0; kt < SEQ / 64; kt++) {
    int k0 = kt * 64;
#pragma unroll
    for (int i = 0; i < 4; i++) {
      int fid = tid + i * 256;
      int r = fid >> 4, c4 = (fid & 15) << 2;
      *(float4*)&Kt[r][c4] = *(const float4*)(xn + (size_t)(k0 + r) * DMODEL + h * 64 + c4);
    }
    __syncthreads();

    float s[4][4] = {};
#pragma unroll 8
    for (int d = 0; d < 64; d++) {
      float qa[4], kb[4];
#pragma unroll
      for (int a = 0; a < 4; a++) qa[a] = Qt[ty * 4 + a][d];
#pragma unroll
      for (int b = 0; b < 4; b++) kb[b] = Kt[tx + 16 * b][d];
#pragma unroll
      for (int a = 0; a < 4; a++)
#pragma unroll
        for (int b = 0; b < 4; b++) s[a][b] = fmaf(qa[a], kb[b], s[a][b]);
    }
#pragma unroll
    for (int a = 0; a < 4; a++)
#pragma unroll
      for (int b = 0; b < 4; b++)
        St[ty * 4 + a][tx + 16 * b] = s[a][b] * 0.125f;  // 1/sqrt(64)
    __syncthreads();

    if (tid < 64) {
      const int q = tid;
      float mold = mrow[q], mnew = mold;
#pragma unroll 8
      for (int k = 0; k < 64; k++) mnew = fmaxf(mnew, St[q][k]);
      float alpha = __expf(mold - mnew);  // exp(-inf)=0 on first tile
      float sum = 0.f;
#pragma unroll 8
      for (int k = 0; k < 64; k++) {
        float p = __expf(St[q][k] - mnew);
        St[q][k] = p;
        sum += p;
      }
      lrow[q] = lrow[q] * alpha + sum;
      mrow[q] = mnew;
      arow[q] = alpha;
    }
    __syncthreads();

    float al[4];
#pragma unroll
    for (int a = 0; a < 4; a++) al[a] = arow[ty * 4 + a];
#pragma unroll
    for (int a = 0; a < 4; a++)
#pragma unroll
      for (int b = 0; b < 4; b++) o[a][b] *= al[a];
#pragma unroll 8
    for (int k = 0; k < 64; k++) {
      float pa[4], vb[4];
#pragma unroll
      for (int a = 0; a < 4; a++) pa[a] = St[ty * 4 + a][k];
#pragma unroll
      for (int b = 0; b < 4; b++) vb[b] = Kt[k][tx + 16 * b];
#pragma unroll
      for (int a = 0; a < 4; a++)
#pragma unroll
        for (int b = 0; b < 4; b++) o[a][b] = fmaf(pa[a], vb[b], o[a][b]);
    }
    __syncthreads();  // before Kt overwrite
  }

#pragma unroll
  for (int a = 0; a < 4; a++) {
    int q = ty * 4 + a;
    float inv = 1.f / lrow[q];
#pragma unroll
    for (int b = 0; b < 4; b++) {
      size_t off = (size_t)(q0 + q) * DMODEL + h * 64 + tx + 16 * b;
      outbuf[off] = x[off] + o[a][b] * inv;
    }
  }
}

// ---------------------------------------------------------------- gate (softmax + top-2)
__global__ __launch_bounds__(256) void gate_kernel(const float* __restrict__ xf,
                                                   const float* __restrict__ gw,
                                                   int* __restrict__ topki,
                                                   float* __restrict__ topkw) {
  int lane = threadIdx.x & 63;
  int t = (blockIdx.x * 256 + threadIdx.x) >> 6;
  if (t >= SEQ) return;
  float acc[NEXP] = {};
  const float* xr = xf + (size_t)t * DMODEL;
  for (int j = 0; j < DMODEL / 64; j++) {
    int d = lane + j * 64;
    float xv = xr[d];
#pragma unroll
    for (int e = 0; e < NEXP; e++) acc[e] = fmaf(xv, gw[e * DMODEL + d], acc[e]);
  }
#pragma unroll
  for (int off = 32; off >= 1; off >>= 1)
#pragma unroll
    for (int e = 0; e < NEXP; e++) acc[e] += __shfl_xor(acc[e], off, 64);
  if (lane == 0) {
    float mx = acc[0];
#pragma unroll
    for (int e = 1; e < NEXP; e++) mx = fmaxf(mx, acc[e]);
    float s = 0.f, p[NEXP];
#pragma unroll
    for (int e = 0; e < NEXP; e++) { p[e] = __expf(acc[e] - mx); s += p[e]; }
    int e0 = 0; float b0 = p[0];
    for (int e = 1; e < NEXP; e++) if (p[e] > b0) { b0 = p[e]; e0 = e; }
    int e1 = -1; float b1v = -1.f;
    for (int e = 0; e < NEXP; e++) if (e != e0 && p[e] > b1v) { b1v = p[e]; e1 = e; }
    float inv = 1.f / s;
    topki[t * 2 + 0] = e0;
    topki[t * 2 + 1] = e1;
    topkw[t * 2 + 0] = fmaxf(b0 * inv, 1e-7f);
    topkw[t * 2 + 1] = fmaxf(b1v * inv, 1e-7f);
  }
}

// ---------------------------------------------------------------- routing scatter
__global__ void scatter_kernel(const int* __restrict__ topki, const float* __restrict__ topkw,
                               int* __restrict__ counts, int* __restrict__ toklist,
                               float* __restrict__ wtlist) {
  int t = blockIdx.x * blockDim.x + threadIdx.x;
  if (t >= SEQ) return;
#pragma unroll
  for (int k = 0; k < 2; k++) {
    int e = topki[t * 2 + k];
    float w = topkw[t * 2 + k];
    int pos = atomicAdd(&counts[e], 1);
    toklist[e * SEQ + pos] = t;
    wtlist[e * SEQ + pos] = w;
  }
}

__global__ void offsets_kernel(const int* __restrict__ counts, int* __restrict__ offsets) {
  if (blockIdx.x == 0 && threadIdx.x == 0) {
    int o = 0;
    for (int e = 0; e < NEXP; e++) { offsets[e] = o; o += counts[e]; }
  }
}

// ---------------------------------------------------------------- GEMM core
// C[m][n] = sum_k A[rowIdx[m]][k] * W[n0+n][k]   (both row-major over k)
// 128x128 tile, 256 threads, 8x8 micro-tile (rows blocked, cols cyclic).
__device__ __forceinline__ void gemm_tile_acc(
    const float* __restrict__ A, int lda,
    const float* __restrict__ W, int n0, int ldw,
    int Kdim, const int* __restrict__ rowIdx,
    float (&acc)[8][8], float (*As)[17], float (*Ws)[17], int tid) {
  const int tx = tid & 15, ty = tid >> 4;
  for (int k0 = 0; k0 < Kdim; k0 += 16) {
#pragma unroll
    for (int i = 0; i < 2; i++) {
      int fid = tid + i * 256;
      int r = fid >> 2, c4 = (fid & 3) << 2;
      float4 av = *(const float4*)(A + (size_t)rowIdx[r] * lda + k0 + c4);
      As[r][c4 + 0] = av.x; As[r][c4 + 1] = av.y; As[r][c4 + 2] = av.z; As[r][c4 + 3] = av.w;
      float4 wv = *(const float4*)(W + (size_t)(n0 + r) * ldw + k0 + c4);
      Ws[r][c4 + 0] = wv.x; Ws[r][c4 + 1] = wv.y; Ws[r][c4 + 2] = wv.z; Ws[r][c4 + 3] = wv.w;
    }
    __syncthreads();
#pragma unroll
    for (int k = 0; k < 16; k++) {
      float a[8], w[8];
#pragma unroll
      for (int i = 0; i < 8; i++) a[i] = As[ty * 8 + i][k];
#pragma unroll
      for (int j = 0; j < 8; j++) w[j] = Ws[tx + 16 * j][k];
#pragma unroll
      for (int i = 0; i < 8; i++)
#pragma unroll
        for (int j = 0; j < 8; j++) acc[i][j] = fmaf(a[i], w[j], acc[i][j]);
    }
    __syncthreads();
  }
}

// ---------------------------------------------------------------- expert MLP pass 1
// phase 0: hbuf = xf @ w1^T + b1        (raw gate pre-activation)
// phase 1: hbuf = silu(hbuf) * (xf @ w3^T + b3)
__global__ __launch_bounds__(256) void mlp1_kernel(
    const float* __restrict__ xf, const float* __restrict__ wmat,
    const float* __restrict__ bias, const int* __restrict__ counts,
    const int* __restrict__ offsets, const int* __restrict__ toklist,
    float* __restrict__ hbuf, int phase) {
  __shared__ float As[128][17];
  __shared__ float Ws[128][17];
  __shared__ int rowIdx[128];
  const int e = blockIdx.z;
  const int cnt = counts[e];
  const int m0 = blockIdx.y * 128;
  if (m0 >= cnt) return;
  const int n0 = blockIdx.x * 128;
  const int tid = threadIdx.x;
  if (tid < 128) {
    int rr = m0 + tid;
    rowIdx[tid] = toklist[e * SEQ + ((rr < cnt) ? rr : 0)];
  }
  __syncthreads();
  float acc[8][8] = {};
  gemm_tile_acc(xf, DMODEL, wmat + (size_t)e * IDIM * DMODEL, n0, DMODEL, DMODEL,
                rowIdx, acc, As, Ws, tid);
  const int tx = tid & 15, ty = tid >> 4;
  const int off = offsets[e];
#pragma unroll
  for (int i = 0; i < 8; i++) {
    int rr = m0 + ty * 8 + i;
    if (rr >= cnt) continue;
    size_t hr = (size_t)(off + rr) * IDIM;
#pragma unroll
    for (int j = 0; j < 8; j++) {
      int n = n0 + tx + 16 * j;
      float v = acc[i][j] + bias[e * IDIM + n];
      if (phase == 0) {
        hbuf[hr + n] = v;
      } else {
        float av = hbuf[hr + n];
        float sig = 1.f / (1.f + __expf(-av));
        hbuf[hr + n] = av * sig * v;
      }
    }
  }
}

// ---------------------------------------------------------------- expert MLP pass 2
// ybuf[tok] += wt * (h @ w2^T + b2)
__global__ __launch_bounds__(256) void mlp2_kernel(
    const float* __restrict__ hbuf, const float* __restrict__ w2,
    const float* __restrict__ b2, const int* __restrict__ counts,
    const int* __restrict__ offsets, const int* __restrict__ toklist,
    const float* __restrict__ wtlist, float* __restrict__ ybuf) {
  __shared__ float As[128][17];
  __shared__ float Ws[128][17];
  __shared__ int rowIdx[128];
  const int e = blockIdx.z;
  const int cnt = counts[e];
  const int m0 = blockIdx.y * 128;
  if (m0 >= cnt) return;
  const int n0 = blockIdx.x * 128;
  const int tid = threadIdx.x;
  const int off = offsets[e];
  if (tid < 128) {
    int rr = m0 + tid;
    rowIdx[tid] = off + ((rr < cnt) ? rr : 0);
  }
  __syncthreads();
  float acc[8][8] = {};
  gemm_tile_acc(hbuf, IDIM, w2 + (size_t)e * DMODEL * IDIM, n0, IDIM, IDIM,
                rowIdx, acc, As, Ws, tid);
  const int tx = tid & 15, ty = tid >> 4;
#pragma unroll
  for (int i = 0; i < 8; i++) {
    int rr = m0 + ty * 8 + i;
    if (rr >= cnt) continue;
    int tok = toklist[e * SEQ + rr];
    float wt = wtlist[e * SEQ + rr];
#pragma unroll
    for (int j = 0; j < 8; j++) {
      int n = n0 + tx + 16 * j;
      atomicAdd(&ybuf[(size_t)tok * DMODEL + n], wt * (acc[i][j] + b2[e * DMODEL + n]));
    }
  }
}

// ---------------------------------------------------------------- shared expert
__global__ __launch_bounds__(256) void shared1_kernel(
    const float* __restrict__ xf, const float* __restrict__ fc1_w,
    const float* __restrict__ fc1_b, float* __restrict__ hs) {
  __shared__ float As[128][17];
  __shared__ float Ws[128][17];
  __shared__ int rowIdx[128];
  const int m0 = blockIdx.y * 128, n0 = blockIdx.x * 128;
  const int tid = threadIdx.x;
  if (tid < 128) rowIdx[tid] = m0 + tid;
  __syncthreads();
  float acc[8][8] = {};
  gemm_tile_acc(xf, DMODEL, fc1_w, n0, DMODEL, DMODEL, rowIdx, acc, As, Ws, tid);
  const int tx = tid & 15, ty = tid >> 4;
#pragma unroll
  for (int i = 0; i < 8; i++) {
    int m = m0 + ty * 8 + i;
#pragma unroll
    for (int j = 0; j < 8; j++) {
      int n = n0 + tx + 16 * j;
      float v = acc[i][j] + fc1_b[n];
      hs[(size_t)m * ISH + n] = v / (1.f + __expf(-v));  // silu
    }
  }
}

// out = outbuf + ybuf + hs @ fc2^T + fc2_b   (final fused epilogue)
__global__ __launch_bounds__(256) void shared2_kernel(
    const float* __restrict__ hs, const float* __restrict__ fc2_w,
    const float* __restrict__ fc2_b, const float* __restrict__ outbuf,
    const float* __restrict__ ybuf, float* __restrict__ out) {
  __shared__ float As[128][17];
  __shared__ float Ws[128][17];
  __shared__ int rowIdx[128];
  const int m0 = blockIdx.y * 128, n0 = blockIdx.x * 128;
  const int tid = threadIdx.x;
  if (tid < 128) rowIdx[tid] = m0 + tid;
  __syncthreads();
  float acc[8][8] = {};
  gemm_tile_acc(hs, ISH, fc2_w, n0, ISH, ISH, rowIdx, acc, As, Ws, tid);
  const int tx = tid & 15, ty = tid >> 4;
#pragma unroll
  for (int i = 0; i < 8; i++) {
    int m = m0 + ty * 8 + i;
#pragma unroll
    for (int j = 0; j < 8; j++) {
      int n = n0 + tx + 16 * j;
      size_t idx = (size_t)m * DMODEL + n;
      out[idx] = outbuf[idx] + ybuf[idx] + acc[i][j] + fc2_b[n];
    }
  }
}

// ---------------------------------------------------------------- launch
extern "C" void kernel_launch(void* const* d_in, const int* in_sizes, int n_in,
                              void* d_out, int out_size, void* d_ws, size_t ws_size,
                              hipStream_t stream) {
  const float* x       = (const float*)d_in[0];
  const float* norm1_w = (const float*)d_in[1];
  const float* norm3_w = (const float*)d_in[2];
  const float* gate_w  = (const float*)d_in[3];
  const float* w1      = (const float*)d_in[4];
  const float* b1      = (const float*)d_in[5];
  const float* w2      = (const float*)d_in[6];
  const float* b2      = (const float*)d_in[7];
  const float* w3      = (const float*)d_in[8];
  const float* b3      = (const float*)d_in[9];
  const float* fc1_w   = (const float*)d_in[10];
  const float* fc1_b   = (const float*)d_in[11];
  const float* fc2_w   = (const float*)d_in[12];
  const float* fc2_b   = (const float*)d_in[13];
  float* out = (float*)d_out;

  // workspace layout (floats)
  float* ws      = (float*)d_ws;
  float* xn      = ws;                      // 2048*768
  float* outbuf  = xn + SEQ * DMODEL;       // 2048*768
  float* xf      = outbuf + SEQ * DMODEL;   // 2048*768
  float* ybuf    = xf + SEQ * DMODEL;       // 2048*768
  float* hbuf    = ybuf + SEQ * DMODEL;     // 4096*1024 (exact total expert slots)
  float* hsbuf   = hbuf + (size_t)2 * SEQ * IDIM;  // 2048*2048
  float* topkw   = hsbuf + (size_t)SEQ * ISH;      // 2048*2
  int*   topki   = (int*)(topkw + SEQ * 2);        // 2048*2
  int*   counts  = topki + SEQ * 2;                // 8
  int*   offsets = counts + NEXP;                  // 8
  int*   toklist = offsets + NEXP;                 // 8*2048
  float* wtlist  = (float*)(toklist + NEXP * SEQ); // 8*2048

  zero_kernel<<<SEQ * DMODEL / 4 / 256, 256, 0, stream>>>(ybuf, counts);
  rmsnorm_kernel<<<SEQ, 256, 0, stream>>>(x, norm1_w, xn);
  attn_kernel<<<dim3(SEQ / 64, NHEAD), 256, 0, stream>>>(xn, x, outbuf);
  rmsnorm_kernel<<<SEQ, 256, 0, stream>>>(outbuf, norm3_w, xf);
  gate_kernel<<<SEQ * 64 / 256, 256, 0, stream>>>(xf, gate_w, topki, topkw);
  scatter_kernel<<<SEQ / 256, 256, 0, stream>>>(topki, topkw, counts, toklist, wtlist);
  offsets_kernel<<<1, 64, 0, stream>>>(counts, offsets);
  mlp1_kernel<<<dim3(IDIM / 128, SEQ / 128, NEXP), 256, 0, stream>>>(
      xf, w1, b1, counts, offsets, toklist, hbuf, 0);
  mlp1_kernel<<<dim3(IDIM / 128, SEQ / 128, NEXP), 256, 0, stream>>>(
      xf, w3, b3, counts, offsets, toklist, hbuf, 1);
  mlp2_kernel<<<dim3(DMODEL / 128, SEQ / 128, NEXP), 256, 0, stream>>>(
      hbuf, w2, b2, counts, offsets, toklist, wtlist, ybuf);
  shared1_kernel<<<dim3(ISH / 128, SEQ / 128), 256, 0, stream>>>(xf, fc1_w, fc1_b, hsbuf);
  shared2_kernel<<<dim3(DMODEL / 128, SEQ / 128), 256, 0, stream>>>(
      hsbuf, fc2_w, fc2_b, outbuf, ybuf, out);
  (void)in_sizes; (void)n_in; (void)out_size; (void)ws_size;
}

// Round 2
// 448.977 us; speedup vs baseline: 3.5746x; 3.5746x over previous
//
#include <hip/hip_runtime.h>
#include <math.h>

#define SEQ    2048
#define DMODEL 768
#define NHEAD  12
#define NEXP   8
#define IDIM   1024
#define ISH    2048

typedef unsigned short u16;
typedef short s16x8 __attribute__((ext_vector_type(8)));
typedef u16   u16x8 __attribute__((ext_vector_type(8)));
typedef float f32x4 __attribute__((ext_vector_type(4)));

#define MFMA_BF16(a, b, c) __builtin_amdgcn_mfma_f32_16x16x32_bf16((a), (b), (c), 0, 0, 0)

__device__ __forceinline__ void glds16(const void* g, void* l) {
  __builtin_amdgcn_global_load_lds(
      (const __attribute__((address_space(1))) unsigned int*)g,
      (__attribute__((address_space(3))) unsigned int*)l, 16, 0, 0);
}

__device__ __forceinline__ u16 f2b(float f) {  // fp32 -> bf16 RNE
  unsigned int u = __float_as_uint(f);
  unsigned int r = u + 0x7fffu + ((u >> 16) & 1u);
  return (u16)(r >> 16);
}
__device__ __forceinline__ float b2f(u16 v) {
  return __uint_as_float(((unsigned int)v) << 16);
}

// ---------------------------------------------------------------- fp32 -> bf16 convert
__global__ __launch_bounds__(256) void cvt_kernel(const float* __restrict__ src,
                                                  u16* __restrict__ dst, int n8) {
  int i = blockIdx.x * blockDim.x + threadIdx.x;
  if (i >= n8) return;
  const float4* s4 = (const float4*)src;
  float4 a = s4[2 * i], b = s4[2 * i + 1];
  u16x8 o;
  o[0] = f2b(a.x); o[1] = f2b(a.y); o[2] = f2b(a.z); o[3] = f2b(a.w);
  o[4] = f2b(b.x); o[5] = f2b(b.y); o[6] = f2b(b.z); o[7] = f2b(b.w);
  ((u16x8*)dst)[i] = o;
}

// ---------------------------------------------------------------- zero init
__global__ void zero_kernel(float* __restrict__ ybuf, int* __restrict__ counts) {
  int idx = blockIdx.x * blockDim.x + threadIdx.x;
  if (idx < SEQ * DMODEL / 4) {
    float4 z; z.x = z.y = z.z = z.w = 0.f;
    ((float4*)ybuf)[idx] = z;
  }
  if (idx < NEXP) counts[idx] = 0;
}

// ---------------------------------------------------------------- rmsnorm (fp32 in, bf16 out + optional fp32 out)
__global__ __launch_bounds__(256) void rmsnorm_kernel(const float* __restrict__ in,
                                                      const float* __restrict__ w,
                                                      u16* __restrict__ outb,
                                                      float* __restrict__ outf) {
  int row = blockIdx.x;
  int tid = threadIdx.x;
  const float* r = in + (size_t)row * DMODEL;
  float v0 = r[tid], v1 = r[tid + 256], v2 = r[tid + 512];
  float ss = v0 * v0 + v1 * v1 + v2 * v2;
  __shared__ float red[256];
  red[tid] = ss;
  __syncthreads();
  for (int s = 128; s > 0; s >>= 1) {
    if (tid < s) red[tid] += red[tid + s];
    __syncthreads();
  }
  float rms = rsqrtf(red[0] * (1.f / DMODEL) + 1e-5f);
  float y0 = v0 * rms * w[tid], y1 = v1 * rms * w[tid + 256], y2 = v2 * rms * w[tid + 512];
  u16* ob = outb + (size_t)row * DMODEL;
  ob[tid] = f2b(y0); ob[tid + 256] = f2b(y1); ob[tid + 512] = f2b(y2);
  if (outf) {
    float* of = outf + (size_t)row * DMODEL;
    of[tid] = y0; of[tid + 256] = y1; of[tid + 512] = y2;
  }
}

// ---------------------------------------------------------------- MFMA flash attention
// Per (64-q-row tile, head). Q=K=V=xnb (bf16). outbuf = x + attn (fp32).
__global__ __launch_bounds__(256) void attn_kernel(const u16* __restrict__ xnb,
                                                   const float* __restrict__ x,
                                                   float* __restrict__ outbuf) {
  __shared__ u16 Qs[2][64][32];   // [d-panel][row][d-in-panel] — glds layout, no pad
  __shared__ u16 Ks[2][64][32];
  __shared__ u16 Vt[64][72];      // transposed V: [d][k], pad 72 (144B rows, 16B aligned)
  __shared__ u16 Ps[64][72];      // P in A-operand layout: [q][k]
  const int h = blockIdx.y;
  const int q0 = blockIdx.x * 64;
  const int tid = threadIdx.x;
  const int lane = tid & 63, w = tid >> 6;
  const int quad = lane >> 4, l15 = lane & 15;
  const int rsub = lane >> 2, c8 = (lane & 3) * 8;

  const int sA = 2 * w, sB = 2 * w + 1;
  const int pA = sA >> 2, rA = 16 * (sA & 3) + rsub;
  const int pB = sB >> 2, rB = 16 * (sB & 3) + rsub;
  const size_t hoff = (size_t)h * 64;

  // stage Q once (8 glds insts across 4 waves)
  glds16(xnb + (size_t)(q0 + rA) * DMODEL + hoff + pA * 32 + c8, &Qs[pA][16 * (sA & 3)][0]);
  glds16(xnb + (size_t)(q0 + rB) * DMODEL + hoff + pB * 32 + c8, &Qs[pB][16 * (sB & 3)][0]);
  __syncthreads();

  const s16x8 aq0 = *(const s16x8*)&Qs[0][16 * w + l15][quad * 8];
  const s16x8 aq1 = *(const s16x8*)&Qs[1][16 * w + l15][quad * 8];

  f32x4 o[4] = {};
  float mrow[4], lrow[4];
#pragma unroll
  for (int r = 0; r < 4; r++) { mrow[r] = -INFINITY; lrow[r] = 0.f; }

  for (int kt = 0; kt < SEQ / 64; kt++) {
    const int k0 = kt * 64;
    glds16(xnb + (size_t)(k0 + rA) * DMODEL + hoff + pA * 32 + c8, &Ks[pA][16 * (sA & 3)][0]);
    glds16(xnb + (size_t)(k0 + rB) * DMODEL + hoff + pB * 32 + c8, &Ks[pB][16 * (sB & 3)][0]);
    __syncthreads();  // Ks visible; prior-iter PV (Vt/Ps readers) all done

    // build Vt[d][k] from Ks (paired rows -> b32 writes)
    {
      const int p = tid >> 7, rp = (tid >> 2) & 31, dc = (tid & 3) * 8;
      u16x8 v0 = *(const u16x8*)&Ks[p][2 * rp][dc];
      u16x8 v1 = *(const u16x8*)&Ks[p][2 * rp + 1][dc];
#pragma unroll
      for (int j = 0; j < 8; j++) {
        *(unsigned int*)&Vt[p * 32 + dc + j][2 * rp] =
            (unsigned int)v0[j] | ((unsigned int)v1[j] << 16);
      }
    }

    // QK^T: 16 q-rows (this wave) x 64 k-cols
    f32x4 s4[4] = {};
#pragma unroll
    for (int jt = 0; jt < 4; jt++) {
      s16x8 b0 = *(const s16x8*)&Ks[0][16 * jt + l15][quad * 8];
      s16x8 b1 = *(const s16x8*)&Ks[1][16 * jt + l15][quad * 8];
      s4[jt] = MFMA_BF16(aq0, b0, s4[jt]);
      s4[jt] = MFMA_BF16(aq1, b1, s4[jt]);
      s4[jt] *= 0.125f;  // 1/sqrt(64)
    }

    // online softmax (row = quad*4 + r; reduce across 16 lanes of quad)
#pragma unroll
    for (int r = 0; r < 4; r++) {
      float mx = mrow[r];
#pragma unroll
      for (int jt = 0; jt < 4; jt++) mx = fmaxf(mx, s4[jt][r]);
#pragma unroll
      for (int m = 1; m <= 8; m <<= 1) mx = fmaxf(mx, __shfl_xor(mx, m, 64));
      float al = __expf(mrow[r] - mx);  // first iter: exp(-inf)=0
      mrow[r] = mx;
      float pv[4], sum = 0.f;
#pragma unroll
      for (int jt = 0; jt < 4; jt++) { pv[jt] = __expf(s4[jt][r] - mx); sum += pv[jt]; }
#pragma unroll
      for (int m = 1; m <= 8; m <<= 1) sum += __shfl_xor(sum, m, 64);
      lrow[r] = lrow[r] * al + sum;
#pragma unroll
      for (int jt = 0; jt < 4; jt++) o[jt][r] *= al;
#pragma unroll
      for (int jt = 0; jt < 4; jt++) Ps[16 * w + quad * 4 + r][16 * jt + l15] = f2b(pv[jt]);
    }
    __syncthreads();  // Vt complete (all waves) before PV reads

    // PV: O[q][d] += P[q][k] V[k][d]
    s16x8 ap0 = *(const s16x8*)&Ps[16 * w + l15][quad * 8];
    s16x8 ap1 = *(const s16x8*)&Ps[16 * w + l15][32 + quad * 8];
#pragma unroll
    for (int jt = 0; jt < 4; jt++) {
      s16x8 bv0 = *(const s16x8*)&Vt[16 * jt + l15][quad * 8];
      s16x8 bv1 = *(const s16x8*)&Vt[16 * jt + l15][32 + quad * 8];
      o[jt] = MFMA_BF16(ap0, bv0, o[jt]);
      o[jt] = MFMA_BF16(ap1, bv1, o[jt]);
    }
  }

#pragma unroll
  for (int r = 0; r < 4; r++) {
    float inv = 1.f / lrow[r];
    int q = q0 + 16 * w + quad * 4 + r;
#pragma unroll
    for (int jt = 0; jt < 4; jt++) {
      size_t off = (size_t)q * DMODEL + hoff + 16 * jt + l15;
      outbuf[off] = x[off] + o[jt][r] * inv;
    }
  }
}

// ---------------------------------------------------------------- gate (fp32, softmax + top-2)
__global__ __launch_bounds__(256) void gate_kernel(const float* __restrict__ xf,
                                                   const float* __restrict__ gw,
                                                   int* __restrict__ topki,
                                                   float* __restrict__ topkw) {
  int lane = threadIdx.x & 63;
  int t = (blockIdx.x * 256 + threadIdx.x) >> 6;
  if (t >= SEQ) return;
  float acc[NEXP] = {};
  const float* xr = xf + (size_t)t * DMODEL;
  for (int j = 0; j < DMODEL / 64; j++) {
    int d = lane + j * 64;
    float xv = xr[d];
#pragma unroll
    for (int e = 0; e < NEXP; e++) acc[e] = fmaf(xv, gw[e * DMODEL + d], acc[e]);
  }
#pragma unroll
  for (int off = 32; off >= 1; off >>= 1)
#pragma unroll
    for (int e = 0; e < NEXP; e++) acc[e] += __shfl_xor(acc[e], off, 64);
  if (lane == 0) {
    float mx = acc[0];
#pragma unroll
    for (int e = 1; e < NEXP; e++) mx = fmaxf(mx, acc[e]);
    float s = 0.f, p[NEXP];
#pragma unroll
    for (int e = 0; e < NEXP; e++) { p[e] = __expf(acc[e] - mx); s += p[e]; }
    int e0 = 0; float b0 = p[0];
    for (int e = 1; e < NEXP; e++) if (p[e] > b0) { b0 = p[e]; e0 = e; }
    int e1 = -1; float b1v = -1.f;
    for (int e = 0; e < NEXP; e++) if (e != e0 && p[e] > b1v) { b1v = p[e]; e1 = e; }
    float inv = 1.f / s;
    topki[t * 2 + 0] = e0;
    topki[t * 2 + 1] = e1;
    topkw[t * 2 + 0] = fmaxf(b0 * inv, 1e-7f);
    topkw[t * 2 + 1] = fmaxf(b1v * inv, 1e-7f);
  }
}

// ---------------------------------------------------------------- routing scatter
__global__ void scatter_kernel(const int* __restrict__ topki, const float* __restrict__ topkw,
                               int* __restrict__ counts, int* __restrict__ toklist,
                               float* __restrict__ wtlist) {
  int t = blockIdx.x * blockDim.x + threadIdx.x;
  if (t >= SEQ) return;
#pragma unroll
  for (int k = 0; k < 2; k++) {
    int e = topki[t * 2 + k];
    float w = topkw[t * 2 + k];
    int pos = atomicAdd(&counts[e], 1);
    toklist[e * SEQ + pos] = t;
    wtlist[e * SEQ + pos] = w;
  }
}

__global__ void offsets_kernel(const int* __restrict__ counts, int* __restrict__ offsets) {
  if (blockIdx.x == 0 && threadIdx.x == 0) {
    int o = 0;
    for (int e = 0; e < NEXP; e++) { offsets[e] = o; o += counts[e]; }
  }
}

// ---------------------------------------------------------------- MFMA GEMM core (m97 structure)
// acc[m][n] += sum_k A[rIdx[m]][k] * W[n0+n][k]; bf16 in, fp32 acc.
// 128x128 tile, BK=32, 4 waves (2x2), 4x4 16x16 frags per wave.
__device__ __forceinline__ void gemm_core(const u16* __restrict__ A, int lda,
                                          const u16* __restrict__ W, int ldw,
                                          int n0, int Kdim, const int* rIdx,
                                          u16 (*As)[32], u16 (*Ws)[32],
                                          f32x4 (&acc)[4][4]) {
  const int tid = threadIdx.x, lane = tid & 63, w = tid >> 6;
  const int quad = lane >> 4, l15 = lane & 15;
  const int wy = w >> 1, wx = w & 1;
  const int s0 = 2 * w, s1 = s0 + 1;
  const int rsub = lane >> 2, c8 = (lane & 3) * 8;
  const u16* Ap0 = A + (size_t)rIdx[16 * s0 + rsub] * lda + c8;
  const u16* Ap1 = A + (size_t)rIdx[16 * s1 + rsub] * lda + c8;
  const u16* Wp0 = W + (size_t)(n0 + 16 * s0 + rsub) * ldw + c8;
  const u16* Wp1 = W + (size_t)(n0 + 16 * s1 + rsub) * ldw + c8;
  u16* dA0 = &As[16 * s0][0]; u16* dA1 = &As[16 * s1][0];
  u16* dW0 = &Ws[16 * s0][0]; u16* dW1 = &Ws[16 * s1][0];
  for (int k0 = 0; k0 < Kdim; k0 += 32) {
    glds16(Ap0 + k0, dA0);
    glds16(Ap1 + k0, dA1);
    glds16(Wp0 + k0, dW0);
    glds16(Wp1 + k0, dW1);
    __syncthreads();
    s16x8 af[4], wf[4];
#pragma unroll
    for (int i = 0; i < 4; i++) af[i] = *(const s16x8*)&As[64 * wy + 16 * i + l15][quad * 8];
#pragma unroll
    for (int j = 0; j < 4; j++) wf[j] = *(const s16x8*)&Ws[64 * wx + 16 * j + l15][quad * 8];
#pragma unroll
    for (int i = 0; i < 4; i++)
#pragma unroll
      for (int j = 0; j < 4; j++)
        acc[i][j] = MFMA_BF16(af[i], wf[j], acc[i][j]);
    __syncthreads();
  }
}

// ---------------------------------------------------------------- expert MLP pass 1 (w1 / w3)
// phase 0: hb = bf16(xf @ w1^T + b1)
// phase 1: hb = bf16( silu(hb) * (xf @ w3^T + b3) )
__global__ __launch_bounds__(256) void moe_gemm1(const u16* __restrict__ xfb,
                                                 const u16* __restrict__ wmat,
                                                 const float* __restrict__ bias,
                                                 const int* __restrict__ counts,
                                                 const int* __restrict__ offsets,
                                                 const int* __restrict__ toklist,
                                                 u16* __restrict__ hb, int phase) {
  __shared__ u16 As[128][32];
  __shared__ u16 Ws[128][32];
  __shared__ int rIdx[128];
  const int e = blockIdx.z;
  const int cnt = counts[e];
  const int m0 = blockIdx.y * 128;
  if (m0 >= cnt) return;
  const int n0 = blockIdx.x * 128;
  const int tid = threadIdx.x;
  if (tid < 128) {
    int rr = m0 + tid;
    rIdx[tid] = toklist[e * SEQ + ((rr < cnt) ? rr : 0)];
  }
  __syncthreads();
  f32x4 acc[4][4] = {};
  gemm_core(xfb, DMODEL, wmat + (size_t)e * IDIM * DMODEL, DMODEL, n0, DMODEL, rIdx, As, Ws, acc);
  const int lane = tid & 63, w = tid >> 6;
  const int quad = lane >> 4, l15 = lane & 15;
  const int wy = w >> 1, wx = w & 1;
  const int off = offsets[e];
#pragma unroll
  for (int j = 0; j < 4; j++) {
    int n = n0 + 64 * wx + 16 * j + l15;
    float bj = bias[e * IDIM + n];
#pragma unroll
    for (int i = 0; i < 4; i++) {
#pragma unroll
      for (int r = 0; r < 4; r++) {
        int rr = m0 + 64 * wy + 16 * i + quad * 4 + r;
        if (rr < cnt) {
          size_t idx = (size_t)(off + rr) * IDIM + n;
          float v = acc[i][j][r] + bj;
          if (phase == 0) {
            hb[idx] = f2b(v);
          } else {
            float a = b2f(hb[idx]);
            float hval = a / (1.f + __expf(-a)) * v;
            hb[idx] = f2b(hval);
          }
        }
      }
    }
  }
}

// ---------------------------------------------------------------- expert MLP pass 2 (w2)
__global__ __launch_bounds__(256) void moe_gemm2(const u16* __restrict__ hb,
                                                 const u16* __restrict__ w2b,
                                                 const float* __restrict__ b2,
                                                 const int* __restrict__ counts,
                                                 const int* __restrict__ offsets,
                                                 const int* __restrict__ toklist,
                                                 const float* __restrict__ wtlist,
                                                 float* __restrict__ ybuf) {
  __shared__ u16 As[128][32];
  __shared__ u16 Ws[128][32];
  __shared__ int rIdx[128];
  const int e = blockIdx.z;
  const int cnt = counts[e];
  const int m0 = blockIdx.y * 128;
  if (m0 >= cnt) return;
  const int n0 = blockIdx.x * 128;
  const int tid = threadIdx.x;
  const int off = offsets[e];
  if (tid < 128) {
    int rr = m0 + tid;
    rIdx[tid] = off + ((rr < cnt) ? rr : 0);
  }
  __syncthreads();
  f32x4 acc[4][4] = {};
  gemm_core(hb, IDIM, w2b + (size_t)e * DMODEL * IDIM, IDIM, n0, IDIM, rIdx, As, Ws, acc);
  const int lane = tid & 63, w = tid >> 6;
  const int quad = lane >> 4, l15 = lane & 15;
  const int wy = w >> 1, wx = w & 1;
#pragma unroll
  for (int j = 0; j < 4; j++) {
    int n = n0 + 64 * wx + 16 * j + l15;
    float bj = b2[e * DMODEL + n];
#pragma unroll
    for (int i = 0; i < 4; i++) {
#pragma unroll
      for (int r = 0; r < 4; r++) {
        int rr = m0 + 64 * wy + 16 * i + quad * 4 + r;
        if (rr < cnt) {
          int tok = toklist[e * SEQ + rr];
          float wt = wtlist[e * SEQ + rr];
          atomicAdd(&ybuf[(size_t)tok * DMODEL + n], wt * (acc[i][j][r] + bj));
        }
      }
    }
  }
}

// ---------------------------------------------------------------- shared expert pass 1
__global__ __launch_bounds__(256) void sh_gemm1(const u16* __restrict__ xfb,
                                                const u16* __restrict__ fc1b,
                                                const float* __restrict__ fc1_bias,
                                                u16* __restrict__ hsb) {
  __shared__ u16 As[128][32];
  __shared__ u16 Ws[128][32];
  __shared__ int rIdx[128];
  const int m0 = blockIdx.y * 128, n0 = blockIdx.x * 128;
  const int tid = threadIdx.x;
  if (tid < 128) rIdx[tid] = m0 + tid;
  __syncthreads();
  f32x4 acc[4][4] = {};
  gemm_core(xfb, DMODEL, fc1b, DMODEL, n0, DMODEL, rIdx, As, Ws, acc);
  const int lane = tid & 63, w = tid >> 6;
  const int quad = lane >> 4, l15 = lane & 15;
  const int wy = w >> 1, wx = w & 1;
#pragma unroll
  for (int j = 0; j < 4; j++) {
    int n = n0 + 64 * wx + 16 * j + l15;
    float bj = fc1_bias[n];
#pragma unroll
    for (int i = 0; i < 4; i++) {
#pragma unroll
      for (int r = 0; r < 4; r++) {
        int m = m0 + 64 * wy + 16 * i + quad * 4 + r;
        float v = acc[i][j][r] + bj;
        hsb[(size_t)m * ISH + n] = f2b(v / (1.f + __expf(-v)));
      }
    }
  }
}

// ---------------------------------------------------------------- shared expert pass 2 + final combine
__global__ __launch_bounds__(256) void sh_gemm2(const u16* __restrict__ hsb,
                                                const u16* __restrict__ fc2b,
                                                const float* __restrict__ fc2_bias,
                                                const float* __restrict__ outbuf,
                                                const float* __restrict__ ybuf,
                                                float* __restrict__ out) {
  __shared__ u16 As[128][32];
  __shared__ u16 Ws[128][32];
  __shared__ int rIdx[128];
  const int m0 = blockIdx.y * 128, n0 = blockIdx.x * 128;
  const int tid = threadIdx.x;
  if (tid < 128) rIdx[tid] = m0 + tid;
  __syncthreads();
  f32x4 acc[4][4] = {};
  gemm_core(hsb, ISH, fc2b, ISH, n0, ISH, rIdx, As, Ws, acc);
  const int lane = tid & 63, w = tid >> 6;
  const int quad = lane >> 4, l15 = lane & 15;
  const int wy = w >> 1, wx = w & 1;
#pragma unroll
  for (int j = 0; j < 4; j++) {
    int n = n0 + 64 * wx + 16 * j + l15;
    float bj = fc2_bias[n];
#pragma unroll
    for (int i = 0; i < 4; i++) {
#pragma unroll
      for (int r = 0; r < 4; r++) {
        int m = m0 + 64 * wy + 16 * i + quad * 4 + r;
        size_t idx = (size_t)m * DMODEL + n;
        out[idx] = outbuf[idx] + ybuf[idx] + acc[i][j][r] + bj;
      }
    }
  }
}

// ---------------------------------------------------------------- launch
extern "C" void kernel_launch(void* const* d_in, const int* in_sizes, int n_in,
                              void* d_out, int out_size, void* d_ws, size_t ws_size,
                              hipStream_t stream) {
  const float* x       = (const float*)d_in[0];
  const float* norm1_w = (const float*)d_in[1];
  const float* norm3_w = (const float*)d_in[2];
  const float* gate_w  = (const float*)d_in[3];
  const float* w1      = (const float*)d_in[4];
  const float* b1      = (const float*)d_in[5];
  const float* w2      = (const float*)d_in[6];
  const float* b2      = (const float*)d_in[7];
  const float* w3      = (const float*)d_in[8];
  const float* b3      = (const float*)d_in[9];
  const float* fc1_w   = (const float*)d_in[10];
  const float* fc1_b   = (const float*)d_in[11];
  const float* fc2_w   = (const float*)d_in[12];
  const float* fc2_b   = (const float*)d_in[13];
  float* out = (float*)d_out;

  // workspace layout
  char* p = (char*)d_ws;
  u16*   xnb    = (u16*)p;   p += (size_t)SEQ * DMODEL * 2;
  float* outbuf = (float*)p; p += (size_t)SEQ * DMODEL * 4;
  float* xff    = (float*)p; p += (size_t)SEQ * DMODEL * 4;
  u16*   xfb    = (u16*)p;   p += (size_t)SEQ * DMODEL * 2;
  float* ybuf   = (float*)p; p += (size_t)SEQ * DMODEL * 4;
  u16*   hb     = (u16*)p;   p += (size_t)2 * SEQ * IDIM * 2;
  u16*   hsb    = (u16*)p;   p += (size_t)SEQ * ISH * 2;
  u16*   w1b    = (u16*)p;   p += (size_t)NEXP * IDIM * DMODEL * 2;
  u16*   w3b    = (u16*)p;   p += (size_t)NEXP * IDIM * DMODEL * 2;
  u16*   w2b    = (u16*)p;   p += (size_t)NEXP * DMODEL * IDIM * 2;
  u16*   fc1b   = (u16*)p;   p += (size_t)ISH * DMODEL * 2;
  u16*   fc2b   = (u16*)p;   p += (size_t)DMODEL * ISH * 2;
  float* topkw  = (float*)p; p += (size_t)SEQ * 2 * 4;
  int*   topki  = (int*)p;   p += (size_t)SEQ * 2 * 4;
  int*   counts = (int*)p;   p += 256;
  int*   offsets= (int*)p;   p += 256;
  int*   toklist= (int*)p;   p += (size_t)NEXP * SEQ * 4;
  float* wtlist = (float*)p; p += (size_t)NEXP * SEQ * 4;

  const int NW = NEXP * IDIM * DMODEL;       // 6291456
  const int NFC = ISH * DMODEL;              // 1572864
  cvt_kernel<<<(NW / 8 + 255) / 256, 256, 0, stream>>>(w1, w1b, NW / 8);
  cvt_kernel<<<(NW / 8 + 255) / 256, 256, 0, stream>>>(w3, w3b, NW / 8);
  cvt_kernel<<<(NW / 8 + 255) / 256, 256, 0, stream>>>(w2, w2b, NW / 8);
  cvt_kernel<<<(NFC / 8 + 255) / 256, 256, 0, stream>>>(fc1_w, fc1b, NFC / 8);
  cvt_kernel<<<(NFC / 8 + 255) / 256, 256, 0, stream>>>(fc2_w, fc2b, NFC / 8);

  zero_kernel<<<SEQ * DMODEL / 4 / 256, 256, 0, stream>>>(ybuf, counts);
  rmsnorm_kernel<<<SEQ, 256, 0, stream>>>(x, norm1_w, xnb, nullptr);
  attn_kernel<<<dim3(SEQ / 64, NHEAD), 256, 0, stream>>>(xnb, x, outbuf);
  rmsnorm_kernel<<<SEQ, 256, 0, stream>>>(outbuf, norm3_w, xfb, xff);
  gate_kernel<<<SEQ * 64 / 256, 256, 0, stream>>>(xff, gate_w, topki, topkw);
  scatter_kernel<<<SEQ / 256, 256, 0, stream>>>(topki, topkw, counts, toklist, wtlist);
  offsets_kernel<<<1, 64, 0, stream>>>(counts, offsets);
  moe_gemm1<<<dim3(IDIM / 128, SEQ / 128, NEXP), 256, 0, stream>>>(
      xfb, w1b, b1, counts, offsets, toklist, hb, 0);
  moe_gemm1<<<dim3(IDIM / 128, SEQ / 128, NEXP), 256, 0, stream>>>(
      xfb, w3b, b3, counts, offsets, toklist, hb, 1);
  moe_gemm2<<<dim3(DMODEL / 128, SEQ / 128, NEXP), 256, 0, stream>>>(
      hb, w2b, b2, counts, offsets, toklist, wtlist, ybuf);
  sh_gemm1<<<dim3(ISH / 128, SEQ / 128), 256, 0, stream>>>(xfb, fc1b, fc1_b, hsb);
  sh_gemm2<<<dim3(DMODEL / 128, SEQ / 128), 256, 0, stream>>>(
      hsb, fc2b, fc2_b, outbuf, ybuf, out);
  (void)in_sizes; (void)n_in; (void)out_size; (void)ws_size;
}

// Round 3
// 377.574 us; speedup vs baseline: 4.2506x; 1.1891x over previous
//
#include <hip/hip_runtime.h>
#include <math.h>

#define SEQ    2048
#define DMODEL 768
#define NHEAD  12
#define NEXP   8
#define IDIM   1024
#define ISH    2048
#define KVS    4
#define NE2    10   // 8 routed experts + 2 shared-expert halves

typedef unsigned short u16;
typedef short s16x8 __attribute__((ext_vector_type(8)));
typedef u16   u16x8 __attribute__((ext_vector_type(8)));
typedef float f32x4 __attribute__((ext_vector_type(4)));

#define MFMA_BF16(a, b, c) __builtin_amdgcn_mfma_f32_16x16x32_bf16((a), (b), (c), 0, 0, 0)

__device__ __forceinline__ void glds16(const void* g, void* l) {
  __builtin_amdgcn_global_load_lds(
      (const __attribute__((address_space(1))) unsigned int*)g,
      (__attribute__((address_space(3))) unsigned int*)l, 16, 0, 0);
}

__device__ __forceinline__ u16 f2b(float f) {  // fp32 -> bf16 RNE
  unsigned int u = __float_as_uint(f);
  unsigned int r = u + 0x7fffu + ((u >> 16) & 1u);
  return (u16)(r >> 16);
}
__device__ __forceinline__ float b2f(u16 v) {
  return __uint_as_float(((unsigned int)v) << 16);
}

// ---------------------------------------------------------------- cvt all weights + zero counts
__global__ __launch_bounds__(256) void cvt_all_kernel(
    const float* __restrict__ w1, const float* __restrict__ w3, const float* __restrict__ w2,
    const float* __restrict__ fc1, const float* __restrict__ fc2,
    u16* __restrict__ w1b, u16* __restrict__ w3b, u16* __restrict__ w2b,
    u16* __restrict__ fc1b, u16* __restrict__ fc2b, int* __restrict__ counts) {
  if (blockIdx.x == 0 && threadIdx.x < 16) counts[threadIdx.x] = 0;
  long i = (long)blockIdx.x * 256 + threadIdx.x;
  const long NW8 = (long)NEXP * IDIM * DMODEL / 8;   // 786432
  const long NF8 = (long)ISH * DMODEL / 8;           // 196608
  const float* s; u16* d; long o;
  if      (i < NW8)             { s = w1;  d = w1b;  o = i; }
  else if (i < 2 * NW8)         { s = w3;  d = w3b;  o = i - NW8; }
  else if (i < 3 * NW8)         { s = w2;  d = w2b;  o = i - 2 * NW8; }
  else if (i < 3 * NW8 + NF8)   { s = fc1; d = fc1b; o = i - 3 * NW8; }
  else if (i < 3 * NW8 + 2*NF8) { s = fc2; d = fc2b; o = i - 3 * NW8 - NF8; }
  else return;
  float4 a = ((const float4*)s)[2 * o], b = ((const float4*)s)[2 * o + 1];
  u16x8 v;
  v[0] = f2b(a.x); v[1] = f2b(a.y); v[2] = f2b(a.z); v[3] = f2b(a.w);
  v[4] = f2b(b.x); v[5] = f2b(b.y); v[6] = f2b(b.z); v[7] = f2b(b.w);
  ((u16x8*)d)[o] = v;
}

// ---------------------------------------------------------------- rmsnorm (fp32 in, bf16 out)
__global__ __launch_bounds__(256) void rmsnorm_kernel(const float* __restrict__ in,
                                                      const float* __restrict__ w,
                                                      u16* __restrict__ outb) {
  int row = blockIdx.x;
  int tid = threadIdx.x;
  const float* r = in + (size_t)row * DMODEL;
  float v0 = r[tid], v1 = r[tid + 256], v2 = r[tid + 512];
  float ss = v0 * v0 + v1 * v1 + v2 * v2;
  __shared__ float red[256];
  red[tid] = ss;
  __syncthreads();
  for (int s = 128; s > 0; s >>= 1) {
    if (tid < s) red[tid] += red[tid + s];
    __syncthreads();
  }
  float rms = rsqrtf(red[0] * (1.f / DMODEL) + 1e-5f);
  u16* ob = outb + (size_t)row * DMODEL;
  ob[tid]       = f2b(v0 * rms * w[tid]);
  ob[tid + 256] = f2b(v1 * rms * w[tid + 256]);
  ob[tid + 512] = f2b(v2 * rms * w[tid + 512]);
}

// ---------------------------------------------------------------- MFMA flash attention, kv-split
// grid (SEQ/64, NHEAD, KVS). Partials: O (bf16, unnormalized), m, l.
__global__ __launch_bounds__(256) void attn_kernel(const u16* __restrict__ xnb,
                                                   u16* __restrict__ Opart,
                                                   float* __restrict__ Mpart,
                                                   float* __restrict__ Lpart) {
  __shared__ u16 Qs[64][72];   // stride 72 u16 = 144 B: 16B-aligned, 36-bank rows
  __shared__ u16 Ks[64][72];
  __shared__ u16 Vt[64][72];   // transposed V: [d][k]
  __shared__ u16 Ps[64][72];   // P in A-layout: [q][k]
  const int h = blockIdx.y, kvs = blockIdx.z;
  const int q0 = blockIdx.x * 64;
  const int tid = threadIdx.x;
  const int lane = tid & 63, w = tid >> 6;
  const int quad = lane >> 4, l15 = lane & 15;
  const size_t hoff = (size_t)h * 64;

  // stage Q (vector loads, padded LDS)
  for (int cc = tid; cc < 512; cc += 256) {
    int row = cc >> 3, col8 = (cc & 7) * 8;
    *(u16x8*)&Qs[row][col8] = *(const u16x8*)(xnb + (size_t)(q0 + row) * DMODEL + hoff + col8);
  }
  __syncthreads();
  const s16x8 aq0 = *(const s16x8*)&Qs[16 * w + l15][quad * 8];
  const s16x8 aq1 = *(const s16x8*)&Qs[16 * w + l15][32 + quad * 8];

  f32x4 o[4] = {};
  float mrow[4], lrow[4];
#pragma unroll
  for (int r = 0; r < 4; r++) { mrow[r] = -INFINITY; lrow[r] = 0.f; }

  const int it0 = kvs * (SEQ / 64 / KVS);
  for (int it = 0; it < SEQ / 64 / KVS; it++) {
    const int k0 = (it0 + it) * 64;
    for (int cc = tid; cc < 512; cc += 256) {
      int row = cc >> 3, col8 = (cc & 7) * 8;
      *(u16x8*)&Ks[row][col8] = *(const u16x8*)(xnb + (size_t)(k0 + row) * DMODEL + hoff + col8);
    }
    __syncthreads();

    // build Vt[d][k] from Ks (rp spread over 32 to spread banks)
    {
      const int rp = tid & 31, dc = ((tid >> 5) & 7) * 8;
      u16x8 v0 = *(const u16x8*)&Ks[2 * rp][dc];
      u16x8 v1 = *(const u16x8*)&Ks[2 * rp + 1][dc];
#pragma unroll
      for (int j = 0; j < 8; j++) {
        *(unsigned int*)&Vt[dc + j][2 * rp] =
            (unsigned int)v0[j] | ((unsigned int)v1[j] << 16);
      }
    }

    // QK^T
    f32x4 s4[4] = {};
#pragma unroll
    for (int jt = 0; jt < 4; jt++) {
      s16x8 b0 = *(const s16x8*)&Ks[16 * jt + l15][quad * 8];
      s16x8 b1 = *(const s16x8*)&Ks[16 * jt + l15][32 + quad * 8];
      s4[jt] = MFMA_BF16(aq0, b0, s4[jt]);
      s4[jt] = MFMA_BF16(aq1, b1, s4[jt]);
      s4[jt] *= 0.125f;  // 1/sqrt(64)
    }

    // online softmax (row q = 16w + quad*4 + r, spread over 16 lanes of quad)
#pragma unroll
    for (int r = 0; r < 4; r++) {
      float mx = mrow[r];
#pragma unroll
      for (int jt = 0; jt < 4; jt++) mx = fmaxf(mx, s4[jt][r]);
#pragma unroll
      for (int m = 1; m <= 8; m <<= 1) mx = fmaxf(mx, __shfl_xor(mx, m, 64));
      float al = __expf(mrow[r] - mx);
      mrow[r] = mx;
      float pv[4], sum = 0.f;
#pragma unroll
      for (int jt = 0; jt < 4; jt++) { pv[jt] = __expf(s4[jt][r] - mx); sum += pv[jt]; }
#pragma unroll
      for (int m = 1; m <= 8; m <<= 1) sum += __shfl_xor(sum, m, 64);
      lrow[r] = lrow[r] * al + sum;
#pragma unroll
      for (int jt = 0; jt < 4; jt++) o[jt][r] *= al;
#pragma unroll
      for (int jt = 0; jt < 4; jt++) Ps[16 * w + quad * 4 + r][16 * jt + l15] = f2b(pv[jt]);
    }
    __syncthreads();  // Vt & Ps complete before PV reads; also fences Ks re-stage

    // PV
    s16x8 ap0 = *(const s16x8*)&Ps[16 * w + l15][quad * 8];
    s16x8 ap1 = *(const s16x8*)&Ps[16 * w + l15][32 + quad * 8];
#pragma unroll
    for (int jt = 0; jt < 4; jt++) {
      s16x8 bv0 = *(const s16x8*)&Vt[16 * jt + l15][quad * 8];
      s16x8 bv1 = *(const s16x8*)&Vt[16 * jt + l15][32 + quad * 8];
      o[jt] = MFMA_BF16(ap0, bv0, o[jt]);
      o[jt] = MFMA_BF16(ap1, bv1, o[jt]);
    }
  }

  // store partials (unnormalized O + m, l)
  const size_t base = ((size_t)kvs * NHEAD + h) * SEQ;
#pragma unroll
  for (int r = 0; r < 4; r++) {
    int q = q0 + 16 * w + quad * 4 + r;
#pragma unroll
    for (int jt = 0; jt < 4; jt++)
      Opart[(base + q) * 64 + 16 * jt + l15] = f2b(o[jt][r]);
    if (l15 == 0) {
      Mpart[base + q] = mrow[r];
      Lpart[base + q] = lrow[r];
    }
  }
}

// ---------------------------------------------------------------- attention combine + residual
__global__ __launch_bounds__(256) void attn_combine_kernel(const u16* __restrict__ Opart,
                                                           const float* __restrict__ Mpart,
                                                           const float* __restrict__ Lpart,
                                                           const float* __restrict__ x,
                                                           float* __restrict__ outbuf) {
  int idx = blockIdx.x * 256 + threadIdx.x;   // over NHEAD*SEQ*64
  int d = idx & 63, r = idx >> 6;             // r = h*SEQ + q
  int h = r >> 11, q = r & (SEQ - 1);
  float M = -INFINITY;
#pragma unroll
  for (int k = 0; k < KVS; k++) M = fmaxf(M, Mpart[(size_t)k * NHEAD * SEQ + r]);
  float L = 0.f, O = 0.f;
#pragma unroll
  for (int k = 0; k < KVS; k++) {
    size_t pr = (size_t)k * NHEAD * SEQ + r;
    float wgt = __expf(Mpart[pr] - M);
    L += wgt * Lpart[pr];
    O += wgt * b2f(Opart[pr * 64 + d]);
  }
  size_t off = (size_t)q * DMODEL + h * 64 + d;
  outbuf[off] = x[off] + O / L;
}

// ---------------------------------------------------------------- gate (rms folded in, softmax + top-2)
__global__ __launch_bounds__(256) void gate_kernel(const float* __restrict__ outbuf,
                                                   const float* __restrict__ n3w,
                                                   const float* __restrict__ gw,
                                                   int* __restrict__ topki,
                                                   float* __restrict__ topkw) {
  int lane = threadIdx.x & 63;
  int t = (blockIdx.x * 256 + threadIdx.x) >> 6;
  if (t >= SEQ) return;
  float acc[NEXP] = {};
  float ss = 0.f;
  const float* xr = outbuf + (size_t)t * DMODEL;
  for (int j = 0; j < DMODEL / 64; j++) {
    int d = lane + j * 64;
    float v = xr[d];
    ss += v * v;
    float xn = v * n3w[d];
#pragma unroll
    for (int e = 0; e < NEXP; e++) acc[e] = fmaf(xn, gw[e * DMODEL + d], acc[e]);
  }
#pragma unroll
  for (int off = 32; off >= 1; off >>= 1) {
    ss += __shfl_xor(ss, off, 64);
#pragma unroll
    for (int e = 0; e < NEXP; e++) acc[e] += __shfl_xor(acc[e], off, 64);
  }
  if (lane == 0) {
    float rms = rsqrtf(ss * (1.f / DMODEL) + 1e-5f);
    float mx = -INFINITY;
#pragma unroll
    for (int e = 0; e < NEXP; e++) { acc[e] *= rms; mx = fmaxf(mx, acc[e]); }
    float s = 0.f, p[NEXP];
#pragma unroll
    for (int e = 0; e < NEXP; e++) { p[e] = __expf(acc[e] - mx); s += p[e]; }
    int e0 = 0; float b0 = p[0];
    for (int e = 1; e < NEXP; e++) if (p[e] > b0) { b0 = p[e]; e0 = e; }
    int e1 = -1; float b1v = -1.f;
    for (int e = 0; e < NEXP; e++) if (e != e0 && p[e] > b1v) { b1v = p[e]; e1 = e; }
    float inv = 1.f / s;
    topki[t * 2 + 0] = e0;
    topki[t * 2 + 1] = e1;
    topkw[t * 2 + 0] = fmaxf(b0 * inv, 1e-7f);
    topkw[t * 2 + 1] = fmaxf(b1v * inv, 1e-7f);
  }
}

// ---------------------------------------------------------------- routing scatter / offsets
__global__ void scatter_kernel(const int* __restrict__ topki, const float* __restrict__ topkw,
                               int* __restrict__ counts, int* __restrict__ toklist,
                               float* __restrict__ wtlist) {
  int t = blockIdx.x * blockDim.x + threadIdx.x;
  if (t >= SEQ) return;
#pragma unroll
  for (int k = 0; k < 2; k++) {
    int e = topki[t * 2 + k];
    float w = topkw[t * 2 + k];
    int pos = atomicAdd(&counts[e], 1);
    toklist[e * SEQ + pos] = t;
    wtlist[e * SEQ + pos] = w;
  }
}

__global__ void offsets_kernel(const int* __restrict__ counts, int* __restrict__ offsets) {
  if (threadIdx.x == 0) {
    int o = 0;
    for (int e = 0; e < NEXP; e++) { offsets[e] = o; o += counts[e]; }
  }
}

// ---------------------------------------------------------------- copy residual into d_out
__global__ __launch_bounds__(256) void copyout_kernel(const float* __restrict__ outbuf,
                                                      float* __restrict__ out) {
  int i = blockIdx.x * 256 + threadIdx.x;
  ((float4*)out)[i] = ((const float4*)outbuf)[i];
}

// ---------------------------------------------------------------- GEMM1: fused SwiGLU, 10 experts
// e<8:  hb[slot] = bf16( silu(xf@w1^T + b1) * (xf@w3^T + b3) )
// e>=8: hb[slot] = bf16( silu(xf@fc1half^T + fc1_b_half) )
__global__ __launch_bounds__(256) void gemm1_kernel(
    const u16* __restrict__ xfb,
    const u16* __restrict__ w1b, const u16* __restrict__ w3b, const u16* __restrict__ fc1b,
    const float* __restrict__ b1, const float* __restrict__ b3, const float* __restrict__ fc1_b,
    const int* __restrict__ counts, const int* __restrict__ offsets,
    const int* __restrict__ toklist, u16* __restrict__ hb) {
  __shared__ u16 As[128][32];
  __shared__ u16 W1s[128][32];
  __shared__ u16 W3s[128][32];
  __shared__ int rIdx[128];
  const int e = blockIdx.z;
  const bool routed = (e < NEXP);
  const int cnt = routed ? counts[e] : SEQ;
  const int m0 = blockIdx.y * 128;
  if (m0 >= cnt) return;
  const int n0 = blockIdx.x * 128;
  const int tid = threadIdx.x;
  if (tid < 128) {
    int rr = m0 + tid;
    rIdx[tid] = routed ? toklist[e * SEQ + (rr < cnt ? rr : cnt - 1)] : rr;
  }
  __syncthreads();
  const u16* W1 = routed ? w1b + (size_t)e * IDIM * DMODEL
                         : fc1b + (size_t)(e - NEXP) * IDIM * DMODEL;
  const u16* W3 = w3b + (size_t)(routed ? e : 0) * IDIM * DMODEL;

  const int lane = tid & 63, w = tid >> 6;
  const int quad = lane >> 4, l15 = lane & 15;
  const int wy = w >> 1, wx = w & 1;
  const int s0 = 2 * w, s1 = s0 + 1;
  const int rsub = lane >> 2, c8 = (lane & 3) * 8;
  const u16* Ap0 = xfb + (size_t)rIdx[16 * s0 + rsub] * DMODEL + c8;
  const u16* Ap1 = xfb + (size_t)rIdx[16 * s1 + rsub] * DMODEL + c8;
  const u16* W1p0 = W1 + (size_t)(n0 + 16 * s0 + rsub) * DMODEL + c8;
  const u16* W1p1 = W1 + (size_t)(n0 + 16 * s1 + rsub) * DMODEL + c8;
  const u16* W3p0 = W3 + (size_t)(n0 + 16 * s0 + rsub) * DMODEL + c8;
  const u16* W3p1 = W3 + (size_t)(n0 + 16 * s1 + rsub) * DMODEL + c8;

  f32x4 acc1[4][4] = {};
  f32x4 acc3[4][4] = {};
  for (int k0 = 0; k0 < DMODEL; k0 += 32) {
    glds16(Ap0 + k0, &As[16 * s0][0]);
    glds16(Ap1 + k0, &As[16 * s1][0]);
    glds16(W1p0 + k0, &W1s[16 * s0][0]);
    glds16(W1p1 + k0, &W1s[16 * s1][0]);
    if (routed) {
      glds16(W3p0 + k0, &W3s[16 * s0][0]);
      glds16(W3p1 + k0, &W3s[16 * s1][0]);
    }
    __syncthreads();
    s16x8 af[4], w1f[4];
#pragma unroll
    for (int i = 0; i < 4; i++) af[i] = *(const s16x8*)&As[64 * wy + 16 * i + l15][quad * 8];
#pragma unroll
    for (int j = 0; j < 4; j++) w1f[j] = *(const s16x8*)&W1s[64 * wx + 16 * j + l15][quad * 8];
#pragma unroll
    for (int i = 0; i < 4; i++)
#pragma unroll
      for (int j = 0; j < 4; j++)
        acc1[i][j] = MFMA_BF16(af[i], w1f[j], acc1[i][j]);
    if (routed) {
      s16x8 w3f[4];
#pragma unroll
      for (int j = 0; j < 4; j++) w3f[j] = *(const s16x8*)&W3s[64 * wx + 16 * j + l15][quad * 8];
#pragma unroll
      for (int i = 0; i < 4; i++)
#pragma unroll
        for (int j = 0; j < 4; j++)
          acc3[i][j] = MFMA_BF16(af[i], w3f[j], acc3[i][j]);
    }
    __syncthreads();
  }

  const int off = routed ? offsets[e] : (2 * SEQ + (e - NEXP) * SEQ);
#pragma unroll
  for (int j = 0; j < 4; j++) {
    int n = n0 + 64 * wx + 16 * j + l15;
    float b1v = routed ? b1[e * IDIM + n] : fc1_b[(e - NEXP) * IDIM + n];
    float b3v = routed ? b3[e * IDIM + n] : 0.f;
#pragma unroll
    for (int i = 0; i < 4; i++) {
#pragma unroll
      for (int r = 0; r < 4; r++) {
        int rr = m0 + 64 * wy + 16 * i + quad * 4 + r;
        if (rr < cnt) {
          float a = acc1[i][j][r] + b1v;
          float g = routed ? (acc3[i][j][r] + b3v) : 1.f;
          float hv = a / (1.f + __expf(-a)) * g;
          hb[(size_t)(off + rr) * IDIM + n] = f2b(hv);
        }
      }
    }
  }
}

// ---------------------------------------------------------------- GEMM2: down-proj, 10 experts
// out[tok] += wt * (h @ W2^T + bias)
__global__ __launch_bounds__(256) void gemm2_kernel(
    const u16* __restrict__ hb,
    const u16* __restrict__ w2b, const u16* __restrict__ fc2b,
    const float* __restrict__ b2, const float* __restrict__ fc2_b,
    const int* __restrict__ counts, const int* __restrict__ offsets,
    const int* __restrict__ toklist, const float* __restrict__ wtlist,
    float* __restrict__ out) {
  __shared__ u16 As[128][32];
  __shared__ u16 Ws[128][32];
  const int e = blockIdx.z;
  const bool routed = (e < NEXP);
  const int cnt = routed ? counts[e] : SEQ;
  const int m0 = blockIdx.y * 128;
  if (m0 >= cnt) return;
  const int n0 = blockIdx.x * 128;
  const int tid = threadIdx.x;
  const int off = routed ? offsets[e] : (2 * SEQ + (e - NEXP) * SEQ);

  const u16* Wb; int ldw, kof;
  if (routed) { Wb = w2b + (size_t)e * DMODEL * IDIM; ldw = IDIM; kof = 0; }
  else        { Wb = fc2b;                            ldw = ISH;  kof = (e - NEXP) * IDIM; }

  const int lane = tid & 63, w = tid >> 6;
  const int quad = lane >> 4, l15 = lane & 15;
  const int wy = w >> 1, wx = w & 1;
  const int s0 = 2 * w, s1 = s0 + 1;
  const int rsub = lane >> 2, c8 = (lane & 3) * 8;
  int ra0 = m0 + 16 * s0 + rsub; ra0 = off + (ra0 < cnt ? ra0 : cnt - 1);
  int ra1 = m0 + 16 * s1 + rsub; ra1 = off + (ra1 < cnt ? ra1 : cnt - 1);
  const u16* Ap0 = hb + (size_t)ra0 * IDIM + c8;
  const u16* Ap1 = hb + (size_t)ra1 * IDIM + c8;
  const u16* Wp0 = Wb + (size_t)(n0 + 16 * s0 + rsub) * ldw + kof + c8;
  const u16* Wp1 = Wb + (size_t)(n0 + 16 * s1 + rsub) * ldw + kof + c8;

  f32x4 acc[4][4] = {};
  for (int k0 = 0; k0 < IDIM; k0 += 32) {
    glds16(Ap0 + k0, &As[16 * s0][0]);
    glds16(Ap1 + k0, &As[16 * s1][0]);
    glds16(Wp0 + k0, &Ws[16 * s0][0]);
    glds16(Wp1 + k0, &Ws[16 * s1][0]);
    __syncthreads();
    s16x8 af[4], wf[4];
#pragma unroll
    for (int i = 0; i < 4; i++) af[i] = *(const s16x8*)&As[64 * wy + 16 * i + l15][quad * 8];
#pragma unroll
    for (int j = 0; j < 4; j++) wf[j] = *(const s16x8*)&Ws[64 * wx + 16 * j + l15][quad * 8];
#pragma unroll
    for (int i = 0; i < 4; i++)
#pragma unroll
      for (int j = 0; j < 4; j++)
        acc[i][j] = MFMA_BF16(af[i], wf[j], acc[i][j]);
    __syncthreads();
  }

#pragma unroll
  for (int j = 0; j < 4; j++) {
    int n = n0 + 64 * wx + 16 * j + l15;
    float bv = routed ? b2[e * DMODEL + n] : (e == NEXP ? fc2_b[n] : 0.f);
#pragma unroll
    for (int i = 0; i < 4; i++) {
#pragma unroll
      for (int r = 0; r < 4; r++) {
        int rr = m0 + 64 * wy + 16 * i + quad * 4 + r;
        if (rr < cnt) {
          int tok; float wt;
          if (routed) { tok = toklist[e * SEQ + rr]; wt = wtlist[e * SEQ + rr]; }
          else        { tok = rr;                    wt = 1.f; }
          atomicAdd(&out[(size_t)tok * DMODEL + n], wt * (acc[i][j][r] + bv));
        }
      }
    }
  }
}

// ---------------------------------------------------------------- launch
extern "C" void kernel_launch(void* const* d_in, const int* in_sizes, int n_in,
                              void* d_out, int out_size, void* d_ws, size_t ws_size,
                              hipStream_t stream) {
  const float* x       = (const float*)d_in[0];
  const float* norm1_w = (const float*)d_in[1];
  const float* norm3_w = (const float*)d_in[2];
  const float* gate_w  = (const float*)d_in[3];
  const float* w1      = (const float*)d_in[4];
  const float* b1      = (const float*)d_in[5];
  const float* w2      = (const float*)d_in[6];
  const float* b2      = (const float*)d_in[7];
  const float* w3      = (const float*)d_in[8];
  const float* b3      = (const float*)d_in[9];
  const float* fc1_w   = (const float*)d_in[10];
  const float* fc1_b   = (const float*)d_in[11];
  const float* fc2_w   = (const float*)d_in[12];
  const float* fc2_b   = (const float*)d_in[13];
  float* out = (float*)d_out;

  // workspace layout
  char* p = (char*)d_ws;
  u16*   xnb    = (u16*)p;   p += (size_t)SEQ * DMODEL * 2;
  float* outbuf = (float*)p; p += (size_t)SEQ * DMODEL * 4;
  u16*   xfb    = (u16*)p;   p += (size_t)SEQ * DMODEL * 2;
  u16*   hb     = (u16*)p;   p += (size_t)4 * SEQ * IDIM * 2;        // 8192 slots
  u16*   Opart  = (u16*)p;   p += (size_t)KVS * NHEAD * SEQ * 64 * 2;
  float* Mpart  = (float*)p; p += (size_t)KVS * NHEAD * SEQ * 4;
  float* Lpart  = (float*)p; p += (size_t)KVS * NHEAD * SEQ * 4;
  u16*   w1b    = (u16*)p;   p += (size_t)NEXP * IDIM * DMODEL * 2;
  u16*   w3b    = (u16*)p;   p += (size_t)NEXP * IDIM * DMODEL * 2;
  u16*   w2b    = (u16*)p;   p += (size_t)NEXP * DMODEL * IDIM * 2;
  u16*   fc1b   = (u16*)p;   p += (size_t)ISH * DMODEL * 2;
  u16*   fc2b   = (u16*)p;   p += (size_t)DMODEL * ISH * 2;
  float* topkw  = (float*)p; p += (size_t)SEQ * 2 * 4;
  int*   topki  = (int*)p;   p += (size_t)SEQ * 2 * 4;
  int*   counts = (int*)p;   p += 256;
  int*   offsets= (int*)p;   p += 256;
  int*   toklist= (int*)p;   p += (size_t)NEXP * SEQ * 4;
  float* wtlist = (float*)p; p += (size_t)NEXP * SEQ * 4;

  const long NW8 = (long)NEXP * IDIM * DMODEL / 8;
  const long NF8 = (long)ISH * DMODEL / 8;
  const int cvt_blocks = (int)((3 * NW8 + 2 * NF8 + 255) / 256);
  cvt_all_kernel<<<cvt_blocks, 256, 0, stream>>>(w1, w3, w2, fc1_w, fc2_w,
                                                 w1b, w3b, w2b, fc1b, fc2b, counts);
  rmsnorm_kernel<<<SEQ, 256, 0, stream>>>(x, norm1_w, xnb);
  attn_kernel<<<dim3(SEQ / 64, NHEAD, KVS), 256, 0, stream>>>(xnb, Opart, Mpart, Lpart);
  attn_combine_kernel<<<NHEAD * SEQ * 64 / 256, 256, 0, stream>>>(Opart, Mpart, Lpart, x, outbuf);
  rmsnorm_kernel<<<SEQ, 256, 0, stream>>>(outbuf, norm3_w, xfb);
  gate_kernel<<<SEQ * 64 / 256, 256, 0, stream>>>(outbuf, norm3_w, gate_w, topki, topkw);
  scatter_kernel<<<SEQ / 256, 256, 0, stream>>>(topki, topkw, counts, toklist, wtlist);
  offsets_kernel<<<1, 64, 0, stream>>>(counts, offsets);
  gemm1_kernel<<<dim3(IDIM / 128, SEQ / 128, NE2), 256, 0, stream>>>(
      xfb, w1b, w3b, fc1b, b1, b3, fc1_b, counts, offsets, toklist, hb);
  copyout_kernel<<<SEQ * DMODEL / 4 / 256, 256, 0, stream>>>(outbuf, out);
  gemm2_kernel<<<dim3(DMODEL / 128, SEQ / 128, NE2), 256, 0, stream>>>(
      hb, w2b, fc2b, b2, fc2_b, counts, offsets, toklist, wtlist, out);
  (void)in_sizes; (void)n_in; (void)out_size; (void)ws_size;
}

// Round 4
// 352.774 us; speedup vs baseline: 4.5495x; 1.0703x over previous
//
#include <hip/hip_runtime.h>
#include <math.h>

#define SEQ    2048
#define DMODEL 768
#define NHEAD  12
#define NEXP   8
#define IDIM   1024
#define ISH    2048
#define KVS    4
#define NE2    10   // 8 routed experts + 2 shared-expert halves

typedef unsigned short u16;
typedef short s16x8 __attribute__((ext_vector_type(8)));
typedef u16   u16x8 __attribute__((ext_vector_type(8)));
typedef float f32x4 __attribute__((ext_vector_type(4)));

#define MFMA_BF16(a, b, c) __builtin_amdgcn_mfma_f32_16x16x32_bf16((a), (b), (c), 0, 0, 0)

__device__ __forceinline__ void glds16(const void* g, void* l) {
  __builtin_amdgcn_global_load_lds(
      (const __attribute__((address_space(1))) unsigned int*)g,
      (__attribute__((address_space(3))) unsigned int*)l, 16, 0, 0);
}

__device__ __forceinline__ u16 f2b(float f) {  // fp32 -> bf16 RNE
  unsigned int u = __float_as_uint(f);
  unsigned int r = u + 0x7fffu + ((u >> 16) & 1u);
  return (u16)(r >> 16);
}
__device__ __forceinline__ float b2f(u16 v) {
  return __uint_as_float(((unsigned int)v) << 16);
}

// ---------------------------------------------------------------- cvt all weights + zero counts
__global__ __launch_bounds__(256) void cvt_all_kernel(
    const float* __restrict__ w1, const float* __restrict__ w3, const float* __restrict__ w2,
    const float* __restrict__ fc1, const float* __restrict__ fc2,
    u16* __restrict__ w1b, u16* __restrict__ w3b, u16* __restrict__ w2b,
    u16* __restrict__ fc1b, u16* __restrict__ fc2b, int* __restrict__ counts) {
  if (blockIdx.x == 0 && threadIdx.x < 16) counts[threadIdx.x] = 0;
  long i = (long)blockIdx.x * 256 + threadIdx.x;
  const long NW8 = (long)NEXP * IDIM * DMODEL / 8;   // 786432
  const long NF8 = (long)ISH * DMODEL / 8;           // 196608
  const float* s; u16* d; long o;
  if      (i < NW8)             { s = w1;  d = w1b;  o = i; }
  else if (i < 2 * NW8)         { s = w3;  d = w3b;  o = i - NW8; }
  else if (i < 3 * NW8)         { s = w2;  d = w2b;  o = i - 2 * NW8; }
  else if (i < 3 * NW8 + NF8)   { s = fc1; d = fc1b; o = i - 3 * NW8; }
  else if (i < 3 * NW8 + 2*NF8) { s = fc2; d = fc2b; o = i - 3 * NW8 - NF8; }
  else return;
  float4 a = ((const float4*)s)[2 * o], b = ((const float4*)s)[2 * o + 1];
  u16x8 v;
  v[0] = f2b(a.x); v[1] = f2b(a.y); v[2] = f2b(a.z); v[3] = f2b(a.w);
  v[4] = f2b(b.x); v[5] = f2b(b.y); v[6] = f2b(b.z); v[7] = f2b(b.w);
  ((u16x8*)d)[o] = v;
}

// ---------------------------------------------------------------- rmsnorm (fp32 in, bf16 out)
__global__ __launch_bounds__(256) void rmsnorm_kernel(const float* __restrict__ in,
                                                      const float* __restrict__ w,
                                                      u16* __restrict__ outb) {
  int row = blockIdx.x;
  int tid = threadIdx.x;
  const float* r = in + (size_t)row * DMODEL;
  float v0 = r[tid], v1 = r[tid + 256], v2 = r[tid + 512];
  float ss = v0 * v0 + v1 * v1 + v2 * v2;
  __shared__ float red[256];
  red[tid] = ss;
  __syncthreads();
  for (int s = 128; s > 0; s >>= 1) {
    if (tid < s) red[tid] += red[tid + s];
    __syncthreads();
  }
  float rms = rsqrtf(red[0] * (1.f / DMODEL) + 1e-5f);
  u16* ob = outb + (size_t)row * DMODEL;
  ob[tid]       = f2b(v0 * rms * w[tid]);
  ob[tid + 256] = f2b(v1 * rms * w[tid + 256]);
  ob[tid + 512] = f2b(v2 * rms * w[tid + 512]);
}

// ---------------------------------------------------------------- MFMA flash attention, kv-split
__global__ __launch_bounds__(256) void attn_kernel(const u16* __restrict__ xnb,
                                                   u16* __restrict__ Opart,
                                                   float* __restrict__ Mpart,
                                                   float* __restrict__ Lpart) {
  __shared__ u16 Qs[64][72];
  __shared__ u16 Ks[64][72];
  __shared__ u16 Vt[64][72];   // transposed V: [d][k]
  __shared__ u16 Ps[64][72];   // P in A-layout: [q][k]
  const int h = blockIdx.y, kvs = blockIdx.z;
  const int q0 = blockIdx.x * 64;
  const int tid = threadIdx.x;
  const int lane = tid & 63, w = tid >> 6;
  const int quad = lane >> 4, l15 = lane & 15;
  const size_t hoff = (size_t)h * 64;

  for (int cc = tid; cc < 512; cc += 256) {
    int row = cc >> 3, col8 = (cc & 7) * 8;
    *(u16x8*)&Qs[row][col8] = *(const u16x8*)(xnb + (size_t)(q0 + row) * DMODEL + hoff + col8);
  }
  __syncthreads();
  const s16x8 aq0 = *(const s16x8*)&Qs[16 * w + l15][quad * 8];
  const s16x8 aq1 = *(const s16x8*)&Qs[16 * w + l15][32 + quad * 8];

  f32x4 o[4] = {};
  float mrow[4], lrow[4];
#pragma unroll
  for (int r = 0; r < 4; r++) { mrow[r] = -INFINITY; lrow[r] = 0.f; }

  const int it0 = kvs * (SEQ / 64 / KVS);
  for (int it = 0; it < SEQ / 64 / KVS; it++) {
    const int k0 = (it0 + it) * 64;
    for (int cc = tid; cc < 512; cc += 256) {
      int row = cc >> 3, col8 = (cc & 7) * 8;
      *(u16x8*)&Ks[row][col8] = *(const u16x8*)(xnb + (size_t)(k0 + row) * DMODEL + hoff + col8);
    }
    __syncthreads();

    {
      const int rp = tid & 31, dc = ((tid >> 5) & 7) * 8;
      u16x8 v0 = *(const u16x8*)&Ks[2 * rp][dc];
      u16x8 v1 = *(const u16x8*)&Ks[2 * rp + 1][dc];
#pragma unroll
      for (int j = 0; j < 8; j++) {
        *(unsigned int*)&Vt[dc + j][2 * rp] =
            (unsigned int)v0[j] | ((unsigned int)v1[j] << 16);
      }
    }

    f32x4 s4[4] = {};
#pragma unroll
    for (int jt = 0; jt < 4; jt++) {
      s16x8 b0 = *(const s16x8*)&Ks[16 * jt + l15][quad * 8];
      s16x8 b1 = *(const s16x8*)&Ks[16 * jt + l15][32 + quad * 8];
      s4[jt] = MFMA_BF16(aq0, b0, s4[jt]);
      s4[jt] = MFMA_BF16(aq1, b1, s4[jt]);
      s4[jt] *= 0.125f;  // 1/sqrt(64)
    }

#pragma unroll
    for (int r = 0; r < 4; r++) {
      float mx = mrow[r];
#pragma unroll
      for (int jt = 0; jt < 4; jt++) mx = fmaxf(mx, s4[jt][r]);
#pragma unroll
      for (int m = 1; m <= 8; m <<= 1) mx = fmaxf(mx, __shfl_xor(mx, m, 64));
      float al = __expf(mrow[r] - mx);
      mrow[r] = mx;
      float pv[4], sum = 0.f;
#pragma unroll
      for (int jt = 0; jt < 4; jt++) { pv[jt] = __expf(s4[jt][r] - mx); sum += pv[jt]; }
#pragma unroll
      for (int m = 1; m <= 8; m <<= 1) sum += __shfl_xor(sum, m, 64);
      lrow[r] = lrow[r] * al + sum;
#pragma unroll
      for (int jt = 0; jt < 4; jt++) o[jt][r] *= al;
#pragma unroll
      for (int jt = 0; jt < 4; jt++) Ps[16 * w + quad * 4 + r][16 * jt + l15] = f2b(pv[jt]);
    }
    __syncthreads();

    s16x8 ap0 = *(const s16x8*)&Ps[16 * w + l15][quad * 8];
    s16x8 ap1 = *(const s16x8*)&Ps[16 * w + l15][32 + quad * 8];
#pragma unroll
    for (int jt = 0; jt < 4; jt++) {
      s16x8 bv0 = *(const s16x8*)&Vt[16 * jt + l15][quad * 8];
      s16x8 bv1 = *(const s16x8*)&Vt[16 * jt + l15][32 + quad * 8];
      o[jt] = MFMA_BF16(ap0, bv0, o[jt]);
      o[jt] = MFMA_BF16(ap1, bv1, o[jt]);
    }
  }

  const size_t base = ((size_t)kvs * NHEAD + h) * SEQ;
#pragma unroll
  for (int r = 0; r < 4; r++) {
    int q = q0 + 16 * w + quad * 4 + r;
#pragma unroll
    for (int jt = 0; jt < 4; jt++)
      Opart[(base + q) * 64 + 16 * jt + l15] = f2b(o[jt][r]);
    if (l15 == 0) {
      Mpart[base + q] = mrow[r];
      Lpart[base + q] = lrow[r];
    }
  }
}

// ---------------------------------------------------------------- fused post-attention:
// combine kv-split partials + residual -> out (fp32), rmsnorm3 -> xfb (bf16),
// gate softmax+top2 -> scatter (counts/toklist/wtlist). One block per token.
__global__ __launch_bounds__(256) void fused_post_kernel(
    const u16* __restrict__ Opart, const float* __restrict__ Mpart,
    const float* __restrict__ Lpart, const float* __restrict__ x,
    const float* __restrict__ n3w, const float* __restrict__ gw,
    u16* __restrict__ xfb, float* __restrict__ out,
    int* __restrict__ counts, int* __restrict__ toklist, float* __restrict__ wtlist) {
  const int t = blockIdx.x;
  const int tid = threadIdx.x;
  __shared__ float Ms[KVS * NHEAD], Ls[KVS * NHEAD];
  __shared__ float red[256];
  __shared__ float gred[4][NEXP];
  if (tid < KVS * NHEAD) {
    Ms[tid] = Mpart[(size_t)tid * SEQ + t];
    Ls[tid] = Lpart[(size_t)tid * SEQ + t];
  }
  __syncthreads();

  float val[3];
  float ss = 0.f;
#pragma unroll
  for (int ii = 0; ii < 3; ii++) {
    int c = tid + ii * 256;
    int h = c >> 6, d = c & 63;
    float M = -INFINITY;
#pragma unroll
    for (int k = 0; k < KVS; k++) M = fmaxf(M, Ms[k * NHEAD + h]);
    float L = 0.f, O = 0.f;
#pragma unroll
    for (int k = 0; k < KVS; k++) {
      float wgt = __expf(Ms[k * NHEAD + h] - M);
      L += wgt * Ls[k * NHEAD + h];
      O += wgt * b2f(Opart[((size_t)(k * NHEAD + h) * SEQ + t) * 64 + d]);
    }
    float v = x[(size_t)t * DMODEL + c] + O / L;
    out[(size_t)t * DMODEL + c] = v;
    val[ii] = v;
    ss += v * v;
  }
  // block-reduce ss
  red[tid] = ss;
  __syncthreads();
  for (int s = 128; s > 0; s >>= 1) {
    if (tid < s) red[tid] += red[tid + s];
    __syncthreads();
  }
  float rms = rsqrtf(red[0] * (1.f / DMODEL) + 1e-5f);

  float ge[NEXP] = {};
#pragma unroll
  for (int ii = 0; ii < 3; ii++) {
    int c = tid + ii * 256;
    float xn = val[ii] * rms * n3w[c];
    xfb[(size_t)t * DMODEL + c] = f2b(xn);
#pragma unroll
    for (int e = 0; e < NEXP; e++) ge[e] = fmaf(xn, gw[e * DMODEL + c], ge[e]);
  }
  const int lane = tid & 63, w = tid >> 6;
#pragma unroll
  for (int off = 32; off >= 1; off >>= 1)
#pragma unroll
    for (int e = 0; e < NEXP; e++) ge[e] += __shfl_xor(ge[e], off, 64);
  if (lane == 0)
#pragma unroll
    for (int e = 0; e < NEXP; e++) gred[w][e] = ge[e];
  __syncthreads();
  if (tid == 0) {
    float p[NEXP], mx = -INFINITY, s = 0.f;
#pragma unroll
    for (int e = 0; e < NEXP; e++) {
      p[e] = gred[0][e] + gred[1][e] + gred[2][e] + gred[3][e];
      mx = fmaxf(mx, p[e]);
    }
#pragma unroll
    for (int e = 0; e < NEXP; e++) { p[e] = __expf(p[e] - mx); s += p[e]; }
    int e0 = 0; float b0 = p[0];
    for (int e = 1; e < NEXP; e++) if (p[e] > b0) { b0 = p[e]; e0 = e; }
    int e1 = -1; float b1v = -1.f;
    for (int e = 0; e < NEXP; e++) if (e != e0 && p[e] > b1v) { b1v = p[e]; e1 = e; }
    float inv = 1.f / s;
    int pos0 = atomicAdd(&counts[e0], 1);
    toklist[e0 * SEQ + pos0] = t;
    wtlist[e0 * SEQ + pos0] = fmaxf(b0 * inv, 1e-7f);
    int pos1 = atomicAdd(&counts[e1], 1);
    toklist[e1 * SEQ + pos1] = t;
    wtlist[e1 * SEQ + pos1] = fmaxf(b1v * inv, 1e-7f);
  }
}

// ---------------------------------------------------------------- GEMM1: fused SwiGLU, 10 experts
// 64x128 tile, 4 waves (2x2), 2x4 frags/wave.
__global__ __launch_bounds__(256) void gemm1_kernel(
    const u16* __restrict__ xfb,
    const u16* __restrict__ w1b, const u16* __restrict__ w3b, const u16* __restrict__ fc1b,
    const float* __restrict__ b1, const float* __restrict__ b3, const float* __restrict__ fc1_b,
    const int* __restrict__ counts, const int* __restrict__ toklist, u16* __restrict__ hb) {
  __shared__ u16 As[64][32];
  __shared__ u16 W1s[128][32];
  __shared__ u16 W3s[128][32];
  __shared__ int rIdx[64];
  const int e = blockIdx.z;
  const bool routed = (e < NEXP);
  int cnt, off;
  if (routed) {
    cnt = counts[e];
    off = 0;
    for (int i = 0; i < e; i++) off += counts[i];
  } else {
    cnt = SEQ;
    off = 2 * SEQ + (e - NEXP) * SEQ;
  }
  const int m0 = blockIdx.y * 64;
  if (m0 >= cnt) return;
  const int n0 = blockIdx.x * 128;
  const int tid = threadIdx.x;
  if (tid < 64) {
    int rr = m0 + tid;
    rIdx[tid] = routed ? toklist[e * SEQ + (rr < cnt ? rr : cnt - 1)] : rr;
  }
  __syncthreads();
  const u16* W1 = routed ? w1b + (size_t)e * IDIM * DMODEL
                         : fc1b + (size_t)(e - NEXP) * IDIM * DMODEL;
  const u16* W3 = w3b + (size_t)(routed ? e : 0) * IDIM * DMODEL;

  const int lane = tid & 63, w = tid >> 6;
  const int quad = lane >> 4, l15 = lane & 15;
  const int wy = w >> 1, wx = w & 1;
  const int rsub = lane >> 2, c8 = (lane & 3) * 8;
  const u16* Ap   = xfb + (size_t)rIdx[16 * w + rsub] * DMODEL + c8;
  const u16* W1p0 = W1 + (size_t)(n0 + 32 * w + rsub) * DMODEL + c8;
  const u16* W1p1 = W1 + (size_t)(n0 + 32 * w + 16 + rsub) * DMODEL + c8;
  const u16* W3p0 = W3 + (size_t)(n0 + 32 * w + rsub) * DMODEL + c8;
  const u16* W3p1 = W3 + (size_t)(n0 + 32 * w + 16 + rsub) * DMODEL + c8;

  f32x4 acc1[2][4] = {};
  f32x4 acc3[2][4] = {};
  for (int k0 = 0; k0 < DMODEL; k0 += 32) {
    glds16(Ap + k0, &As[16 * w][0]);
    glds16(W1p0 + k0, &W1s[32 * w][0]);
    glds16(W1p1 + k0, &W1s[32 * w + 16][0]);
    if (routed) {
      glds16(W3p0 + k0, &W3s[32 * w][0]);
      glds16(W3p1 + k0, &W3s[32 * w + 16][0]);
    }
    __syncthreads();
    s16x8 af[2], w1f[4];
#pragma unroll
    for (int i = 0; i < 2; i++) af[i] = *(const s16x8*)&As[32 * wy + 16 * i + l15][quad * 8];
#pragma unroll
    for (int j = 0; j < 4; j++) w1f[j] = *(const s16x8*)&W1s[64 * wx + 16 * j + l15][quad * 8];
#pragma unroll
    for (int i = 0; i < 2; i++)
#pragma unroll
      for (int j = 0; j < 4; j++)
        acc1[i][j] = MFMA_BF16(af[i], w1f[j], acc1[i][j]);
    if (routed) {
      s16x8 w3f[4];
#pragma unroll
      for (int j = 0; j < 4; j++) w3f[j] = *(const s16x8*)&W3s[64 * wx + 16 * j + l15][quad * 8];
#pragma unroll
      for (int i = 0; i < 2; i++)
#pragma unroll
        for (int j = 0; j < 4; j++)
          acc3[i][j] = MFMA_BF16(af[i], w3f[j], acc3[i][j]);
    }
    __syncthreads();
  }

#pragma unroll
  for (int j = 0; j < 4; j++) {
    int n = n0 + 64 * wx + 16 * j + l15;
    float b1v = routed ? b1[e * IDIM + n] : fc1_b[(e - NEXP) * IDIM + n];
    float b3v = routed ? b3[e * IDIM + n] : 0.f;
#pragma unroll
    for (int i = 0; i < 2; i++) {
#pragma unroll
      for (int r = 0; r < 4; r++) {
        int rr = m0 + 32 * wy + 16 * i + quad * 4 + r;
        if (rr < cnt) {
          float a = acc1[i][j][r] + b1v;
          float g = routed ? (acc3[i][j][r] + b3v) : 1.f;
          float hv = a / (1.f + __expf(-a)) * g;
          hb[(size_t)(off + rr) * IDIM + n] = f2b(hv);
        }
      }
    }
  }
}

// ---------------------------------------------------------------- GEMM2: down-proj, 10 experts
// 64x128 tile; out[tok] += wt * (h @ W2^T + bias)
__global__ __launch_bounds__(256) void gemm2_kernel(
    const u16* __restrict__ hb,
    const u16* __restrict__ w2b, const u16* __restrict__ fc2b,
    const float* __restrict__ b2, const float* __restrict__ fc2_b,
    const int* __restrict__ counts, const int* __restrict__ toklist,
    const float* __restrict__ wtlist, float* __restrict__ out) {
  __shared__ u16 As[64][32];
  __shared__ u16 Ws[128][32];
  const int e = blockIdx.z;
  const bool routed = (e < NEXP);
  int cnt, off;
  if (routed) {
    cnt = counts[e];
    off = 0;
    for (int i = 0; i < e; i++) off += counts[i];
  } else {
    cnt = SEQ;
    off = 2 * SEQ + (e - NEXP) * SEQ;
  }
  const int m0 = blockIdx.y * 64;
  if (m0 >= cnt) return;
  const int n0 = blockIdx.x * 128;
  const int tid = threadIdx.x;

  const u16* Wb; int ldw, kof;
  if (routed) { Wb = w2b + (size_t)e * DMODEL * IDIM; ldw = IDIM; kof = 0; }
  else        { Wb = fc2b;                            ldw = ISH;  kof = (e - NEXP) * IDIM; }

  const int lane = tid & 63, w = tid >> 6;
  const int quad = lane >> 4, l15 = lane & 15;
  const int wy = w >> 1, wx = w & 1;
  const int rsub = lane >> 2, c8 = (lane & 3) * 8;
  int ra = m0 + 16 * w + rsub; ra = off + (ra < cnt ? ra : cnt - 1);
  const u16* Ap  = hb + (size_t)ra * IDIM + c8;
  const u16* Wp0 = Wb + (size_t)(n0 + 32 * w + rsub) * ldw + kof + c8;
  const u16* Wp1 = Wb + (size_t)(n0 + 32 * w + 16 + rsub) * ldw + kof + c8;

  f32x4 acc[2][4] = {};
  for (int k0 = 0; k0 < IDIM; k0 += 32) {
    glds16(Ap + k0, &As[16 * w][0]);
    glds16(Wp0 + k0, &Ws[32 * w][0]);
    glds16(Wp1 + k0, &Ws[32 * w + 16][0]);
    __syncthreads();
    s16x8 af[2], wf[4];
#pragma unroll
    for (int i = 0; i < 2; i++) af[i] = *(const s16x8*)&As[32 * wy + 16 * i + l15][quad * 8];
#pragma unroll
    for (int j = 0; j < 4; j++) wf[j] = *(const s16x8*)&Ws[64 * wx + 16 * j + l15][quad * 8];
#pragma unroll
    for (int i = 0; i < 2; i++)
#pragma unroll
      for (int j = 0; j < 4; j++)
        acc[i][j] = MFMA_BF16(af[i], wf[j], acc[i][j]);
    __syncthreads();
  }

#pragma unroll
  for (int j = 0; j < 4; j++) {
    int n = n0 + 64 * wx + 16 * j + l15;
    float bv = routed ? b2[e * DMODEL + n] : (e == NEXP ? fc2_b[n] : 0.f);
#pragma unroll
    for (int i = 0; i < 2; i++) {
#pragma unroll
      for (int r = 0; r < 4; r++) {
        int rr = m0 + 32 * wy + 16 * i + quad * 4 + r;
        if (rr < cnt) {
          int tok; float wt;
          if (routed) { tok = toklist[e * SEQ + rr]; wt = wtlist[e * SEQ + rr]; }
          else        { tok = rr;                    wt = 1.f; }
          atomicAdd(&out[(size_t)tok * DMODEL + n], wt * (acc[i][j][r] + bv));
        }
      }
    }
  }
}

// ---------------------------------------------------------------- launch
extern "C" void kernel_launch(void* const* d_in, const int* in_sizes, int n_in,
                              void* d_out, int out_size, void* d_ws, size_t ws_size,
                              hipStream_t stream) {
  const float* x       = (const float*)d_in[0];
  const float* norm1_w = (const float*)d_in[1];
  const float* norm3_w = (const float*)d_in[2];
  const float* gate_w  = (const float*)d_in[3];
  const float* w1      = (const float*)d_in[4];
  const float* b1      = (const float*)d_in[5];
  const float* w2      = (const float*)d_in[6];
  const float* b2      = (const float*)d_in[7];
  const float* w3      = (const float*)d_in[8];
  const float* b3      = (const float*)d_in[9];
  const float* fc1_w   = (const float*)d_in[10];
  const float* fc1_b   = (const float*)d_in[11];
  const float* fc2_w   = (const float*)d_in[12];
  const float* fc2_b   = (const float*)d_in[13];
  float* out = (float*)d_out;

  // workspace layout
  char* p = (char*)d_ws;
  u16*   xnb    = (u16*)p;   p += (size_t)SEQ * DMODEL * 2;
  u16*   xfb    = (u16*)p;   p += (size_t)SEQ * DMODEL * 2;
  u16*   hb     = (u16*)p;   p += (size_t)4 * SEQ * IDIM * 2;        // 8192 slots
  u16*   Opart  = (u16*)p;   p += (size_t)KVS * NHEAD * SEQ * 64 * 2;
  float* Mpart  = (float*)p; p += (size_t)KVS * NHEAD * SEQ * 4;
  float* Lpart  = (float*)p; p += (size_t)KVS * NHEAD * SEQ * 4;
  u16*   w1b    = (u16*)p;   p += (size_t)NEXP * IDIM * DMODEL * 2;
  u16*   w3b    = (u16*)p;   p += (size_t)NEXP * IDIM * DMODEL * 2;
  u16*   w2b    = (u16*)p;   p += (size_t)NEXP * DMODEL * IDIM * 2;
  u16*   fc1b   = (u16*)p;   p += (size_t)ISH * DMODEL * 2;
  u16*   fc2b   = (u16*)p;   p += (size_t)DMODEL * ISH * 2;
  int*   counts = (int*)p;   p += 256;
  int*   toklist= (int*)p;   p += (size_t)NEXP * SEQ * 4;
  float* wtlist = (float*)p; p += (size_t)NEXP * SEQ * 4;

  const long NW8 = (long)NEXP * IDIM * DMODEL / 8;
  const long NF8 = (long)ISH * DMODEL / 8;
  const int cvt_blocks = (int)((3 * NW8 + 2 * NF8 + 255) / 256);
  cvt_all_kernel<<<cvt_blocks, 256, 0, stream>>>(w1, w3, w2, fc1_w, fc2_w,
                                                 w1b, w3b, w2b, fc1b, fc2b, counts);
  rmsnorm_kernel<<<SEQ, 256, 0, stream>>>(x, norm1_w, xnb);
  attn_kernel<<<dim3(SEQ / 64, NHEAD, KVS), 256, 0, stream>>>(xnb, Opart, Mpart, Lpart);
  fused_post_kernel<<<SEQ, 256, 0, stream>>>(Opart, Mpart, Lpart, x, norm3_w, gate_w,
                                             xfb, out, counts, toklist, wtlist);
  gemm1_kernel<<<dim3(IDIM / 128, SEQ / 64, NE2), 256, 0, stream>>>(
      xfb, w1b, w3b, fc1b, b1, b3, fc1_b, counts, toklist, hb);
  gemm2_kernel<<<dim3(DMODEL / 128, SEQ / 64, NE2), 256, 0, stream>>>(
      hb, w2b, fc2b, b2, fc2_b, counts, toklist, wtlist, out);
  (void)in_sizes; (void)n_in; (void)out_size; (void)ws_size;
}